// Round 11
// baseline (1147.008 us; speedup 1.0000x reference)
//
#include <hip/hip_runtime.h>

constexpr int Bc = 8, Nc = 4096, Dc = 256, Hc = 8;
constexpr int TN = 16;    // rows per workgroup in K1
constexpr int TN3 = 32;   // rows per workgroup in K3
constexpr int XS3 = 36;

using short8 = __attribute__((ext_vector_type(8))) short;
using f32x4  = __attribute__((ext_vector_type(4))) float;

static __device__ __forceinline__ unsigned short f2bf(float f) {
    unsigned u = __float_as_uint(f);
    u += 0x7fffu + ((u >> 16) & 1u);     // RNE
    return (unsigned short)(u >> 16);
}
static __device__ __forceinline__ float bf2f(unsigned short h) {
    return __uint_as_float(((unsigned)h) << 16);
}
// XOR-swizzled byte offset for a [16][256] ushort LDS plane (16B-read safe)
static __device__ __forceinline__ int swz(int r, int k) {
    return (r << 9) + ((k << 1) ^ ((r & 7) << 4));
}

// ---------------- K0a: Wd [h][d][e] f32 -> WdT [h][e][d] bf16 ----------------
__global__ __launch_bounds__(256)
void k0_wdt(const float* __restrict__ Wd, unsigned short* __restrict__ WdT)
{
    __shared__ float tile[64][65];
    const int h  = blockIdx.x >> 4;
    const int t  = blockIdx.x & 15;
    const int kb = (t >> 2) * 64, eb = (t & 3) * 64;
    const int tid = threadIdx.x;
    {
        const int krow = tid >> 2, ec = (tid & 3) * 16;
        const float* src = Wd + h * 65536 + (kb + krow) * 256 + eb + ec;
        #pragma unroll
        for (int i = 0; i < 4; ++i) {
            float4 v = *reinterpret_cast<const float4*>(src + i * 4);
            tile[krow][ec + i * 4 + 0] = v.x;
            tile[krow][ec + i * 4 + 1] = v.y;
            tile[krow][ec + i * 4 + 2] = v.z;
            tile[krow][ec + i * 4 + 3] = v.w;
        }
    }
    __syncthreads();
    {
        const int erow = tid >> 2, dc = (tid & 3) * 16;
        unsigned short o[16];
        #pragma unroll
        for (int i = 0; i < 16; ++i) o[i] = f2bf(tile[dc + i][erow]);
        unsigned short* dst = WdT + h * 65536 + (eb + erow) * 256 + kb + dc;
        *reinterpret_cast<short8*>(dst)     = *reinterpret_cast<short8*>(&o[0]);
        *reinterpret_cast<short8*>(dst + 8) = *reinterpret_cast<short8*>(&o[8]);
    }
}

// ---------------- K0b: Wh [k][h][e] f32 -> WhH/WhL [h][e][k] bf16 hi/lo ----------------
__global__ __launch_bounds__(256)
void k0_whsplit(const float* __restrict__ Wh,
                unsigned short* __restrict__ WhH, unsigned short* __restrict__ WhL)
{
    __shared__ float tile[64][65];
    const int h  = blockIdx.x >> 4;
    const int t  = blockIdx.x & 15;
    const int kb = (t >> 2) * 64, eb = (t & 3) * 64;
    const int tid = threadIdx.x;
    {
        const int krow = tid >> 2, ec = (tid & 3) * 16;
        const float* src = Wh + (kb + krow) * 2048 + h * 256 + eb + ec;
        #pragma unroll
        for (int i = 0; i < 4; ++i) {
            float4 v = *reinterpret_cast<const float4*>(src + i * 4);
            tile[krow][ec + i * 4 + 0] = v.x;
            tile[krow][ec + i * 4 + 1] = v.y;
            tile[krow][ec + i * 4 + 2] = v.z;
            tile[krow][ec + i * 4 + 3] = v.w;
        }
    }
    __syncthreads();
    {
        const int erow = tid >> 2, dc = (tid & 3) * 16;
        unsigned short oh[16], ol[16];
        #pragma unroll
        for (int i = 0; i < 16; ++i) {
            float v = tile[dc + i][erow];
            unsigned short hi = f2bf(v);
            oh[i] = hi;
            ol[i] = f2bf(v - bf2f(hi));
        }
        const long base = (long)h * 65536 + (eb + erow) * 256 + kb + dc;
        *reinterpret_cast<short8*>(WhH + base)     = *reinterpret_cast<short8*>(&oh[0]);
        *reinterpret_cast<short8*>(WhH + base + 8) = *reinterpret_cast<short8*>(&oh[8]);
        *reinterpret_cast<short8*>(WhL + base)     = *reinterpret_cast<short8*>(&ol[0]);
        *reinterpret_cast<short8*>(WhL + base + 8) = *reinterpret_cast<short8*>(&ol[8]);
    }
}

// LDS layout offsets (bytes) for K1
#define XSH_OFF 0        // [16][256] ushort swizzled (x hi)
#define XSL_OFF 8192     // [16][256] ushort swizzled (x lo)
#define QTB_OFF 16384    // [16][256] ushort swizzled (q bf16, per h)
#define LSH_OFF 24576    // int[256][16]  (lsh[e][r])
#define PE_OFF  40960    // float[256]
#define CF_OFF  41984    // float[256]
#define CNT_OFF 43008    // int[16][16]
#define FCN_OFF 44032    // int
#define FLS_OFF 44048    // int[1024]

// ---------------- K1: MFMA head GEMM (split-bf16 + exact-sign guard) + MFMA down GEMM ----------------
__global__ __launch_bounds__(256, 3)
void k1_head_down(const float* __restrict__ x,
                  const float* __restrict__ Wh, const float* __restrict__ bh,
                  const unsigned short* __restrict__ WhH, const unsigned short* __restrict__ WhL,
                  const unsigned short* __restrict__ WdT, const float* __restrict__ bd,
                  float* __restrict__ z, float* __restrict__ simv)
{
    __shared__ __align__(16) char SM[49152];

    const int tid = threadIdx.x;
    const long rowbase = (long)blockIdx.x * TN;
    const int wavei = tid >> 6, lane = tid & 63;
    const int mrow = lane & 15, kgrp = lane >> 4;

    {   // XLA:CPU twin tables (CR libm via f64-round)
        const int d = tid;
        const float u = -((float)d * 0.00390625f);
        const float freq = (float)pow(10.0, (double)u);
        const float pe = (d & 1) ? (float)sin((double)freq)
                                 : (float)cos((double)freq);
        ((float*)(SM + PE_OFF))[d] = __fdiv_rn(pe, 0.4f);
        ((float*)(SM + CF_OFF))[d] = __fmul_rn(0.4f, (float)pow((double)0.6f, (double)d));
    }
    if (tid == 0) *((int*)(SM + FCN_OFF)) = 0;
    {   // x -> split bf16 LDS (swizzled): thread handles row r, 16 k
        const int r = tid >> 4, kc = (tid & 15) * 16;
        const float* src = x + (rowbase + r) * 256 + kc;
        unsigned short oh[16], ol[16];
        #pragma unroll
        for (int i = 0; i < 16; i += 4) {
            float4 v = *reinterpret_cast<const float4*>(src + i);
            float vv[4] = {v.x, v.y, v.z, v.w};
            #pragma unroll
            for (int j = 0; j < 4; ++j) {
                unsigned short hi = f2bf(vv[j]);
                oh[i + j] = hi;
                ol[i + j] = f2bf(vv[j] - bf2f(hi));
            }
        }
        *reinterpret_cast<short8*>(SM + XSH_OFF + swz(r, kc))     = *reinterpret_cast<short8*>(&oh[0]);
        *reinterpret_cast<short8*>(SM + XSH_OFF + swz(r, kc + 8)) = *reinterpret_cast<short8*>(&oh[8]);
        *reinterpret_cast<short8*>(SM + XSL_OFF + swz(r, kc))     = *reinterpret_cast<short8*>(&ol[0]);
        *reinterpret_cast<short8*>(SM + XSL_OFF + swz(r, kc + 8)) = *reinterpret_cast<short8*>(&ol[8]);
    }

    int lshv[16];          // [nf][reg] sign sums, this lane's (r,e) cells
    #pragma unroll
    for (int i = 0; i < 16; ++i) lshv[i] = 0;
    f32x4 dacc[4];         // down-GEMM accumulators (persist over h)
    #pragma unroll
    for (int nf = 0; nf < 4; ++nf) dacc[nf] = (f32x4){0.f, 0.f, 0.f, 0.f};

    __syncthreads();

    for (int h = 0; h < Hc; ++h) {
        // ---- head GEMM: 4-term split-bf16 MFMA ----
        f32x4 hacc[4];
        #pragma unroll
        for (int nf = 0; nf < 4; ++nf) hacc[nf] = (f32x4){0.f, 0.f, 0.f, 0.f};
        const unsigned short* whh = WhH + (long)h * 65536;
        const unsigned short* whl = WhL + (long)h * 65536;
        #pragma unroll 2
        for (int kt = 0; kt < 8; ++kt) {
            const int k0 = kt * 32 + kgrp * 8;
            short8 afh = *reinterpret_cast<const short8*>(SM + XSH_OFF + swz(mrow, k0));
            short8 afl = *reinterpret_cast<const short8*>(SM + XSL_OFF + swz(mrow, k0));
            #pragma unroll
            for (int nf = 0; nf < 4; ++nf) {
                const int e = wavei * 64 + nf * 16 + mrow;
                short8 bfh = *reinterpret_cast<const short8*>(&whh[e * 256 + k0]);
                short8 bfl = *reinterpret_cast<const short8*>(&whl[e * 256 + k0]);
                hacc[nf] = __builtin_amdgcn_mfma_f32_16x16x32_bf16(afh, bfh, hacc[nf], 0, 0, 0);
                hacc[nf] = __builtin_amdgcn_mfma_f32_16x16x32_bf16(afh, bfl, hacc[nf], 0, 0, 0);
                hacc[nf] = __builtin_amdgcn_mfma_f32_16x16x32_bf16(afl, bfh, hacc[nf], 0, 0, 0);
                hacc[nf] = __builtin_amdgcn_mfma_f32_16x16x32_bf16(afl, bfl, hacc[nf], 0, 0, 0);
            }
        }
        // ---- signs / guard / qTb ----
        #pragma unroll
        for (int nf = 0; nf < 4; ++nf) {
            const int e = wavei * 64 + nf * 16 + mrow;
            const float bias = bh[h * 256 + e];
            #pragma unroll
            for (int reg = 0; reg < 4; ++reg) {
                const int r = kgrp * 4 + reg;
                const float pre = __fadd_rn(hacc[nf][reg], bias);
                const int s = (pre > 0.0f) ? 1 : -1;
                lshv[nf * 4 + reg] += s;
                if (fabsf(pre) < 2e-3f) {
                    int idx = atomicAdd((int*)(SM + FCN_OFF), 1);
                    if (idx < 1024)
                        ((int*)(SM + FLS_OFF))[idx] =
                            r | (e << 4) | (h << 12) | ((s > 0 ? 1 : 0) << 15);
                }
                *reinterpret_cast<unsigned short*>(SM + QTB_OFF + swz(r, e)) =
                    f2bf(fmaxf(pre, 0.0f));
            }
        }
        __syncthreads();   // qTb ready for all waves
        // ---- down GEMM (MFMA, bf16) ----
        const unsigned short* wdh = WdT + (long)h * 65536;
        #pragma unroll 2
        for (int ks = 0; ks < 8; ++ks) {
            const int k0 = ks * 32 + kgrp * 8;
            short8 af = *reinterpret_cast<const short8*>(SM + QTB_OFF + swz(mrow, k0));
            #pragma unroll
            for (int nf = 0; nf < 4; ++nf) {
                const int e = wavei * 64 + nf * 16 + mrow;
                short8 bf = *reinterpret_cast<const short8*>(&wdh[e * 256 + k0]);
                dacc[nf] = __builtin_amdgcn_mfma_f32_16x16x32_bf16(af, bf, dacc[nf], 0, 0, 0);
            }
        }
        __syncthreads();   // qTb free for next h
    }
    // ---- epilogue: z = relu(dacc + bd) ----
    #pragma unroll
    for (int nf = 0; nf < 4; ++nf) {
        const int e = wavei * 64 + nf * 16 + mrow;
        const float b = bd[e];
        #pragma unroll
        for (int reg = 0; reg < 4; ++reg) {
            const int m = kgrp * 4 + reg;
            z[(rowbase + m) * 256 + e] = fmaxf(dacc[nf][reg] + b, 0.0f);
        }
    }
    // ---- lsh base write ----
    {
        int* lshI = (int*)(SM + LSH_OFF);
        #pragma unroll
        for (int nf = 0; nf < 4; ++nf) {
            const int e = wavei * 64 + nf * 16 + mrow;
            #pragma unroll
            for (int reg = 0; reg < 4; ++reg)
                lshI[e * 16 + kgrp * 4 + reg] = lshv[nf * 4 + reg];
        }
    }
    __syncthreads();
    // ---- guard recompute: exact f32 chain for near-zero preacts ----
    {
        int n = *((int*)(SM + FCN_OFF));
        n = n < 1024 ? n : 1024;
        for (int i = tid; i < n; i += 256) {
            const int ent = ((int*)(SM + FLS_OFF))[i];
            const int r = ent & 15, e = (ent >> 4) & 255, h = (ent >> 12) & 7;
            const int fs = ((ent >> 15) & 1) ? 1 : -1;
            const float* xr = x + (rowbase + r) * 256;
            const float* wcol = Wh + h * 256 + e;
            float acc = 0.0f;
            for (int k = 0; k < 256; ++k)
                acc = fmaf(xr[k], wcol[k * 2048], acc);
            const float pre = __fadd_rn(acc, bh[h * 256 + e]);
            const int es = (pre > 0.0f) ? 1 : -1;
            if (es != fs)
                atomicAdd(&((int*)(SM + LSH_OFF))[e * 16 + r], es - fs);
        }
    }
    __syncthreads();
    // ---- tail: stable counting sort + simv (bit-exact, r9-verified) ----
    if (tid < TN) {
        const int r = tid;
        const int* lshI = (const int*)(SM + LSH_OFF);
        const float* pe_over = (const float*)(SM + PE_OFF);
        const float* c_f = (const float*)(SM + CF_OFF);
        int* cw = (int*)(SM + CNT_OFF) + r * 16;
        for (int i = 0; i < 9; ++i) cw[i] = 0;
        for (int d = 0; d < 256; ++d) {
            int vv = lshI[d * 16 + r];
            cw[(vv + 8) >> 1] += 1;
        }
        int run = 0;
        for (int bin = 8; bin >= 0; --bin) { int c0 = cw[bin]; cw[bin] = run; run += c0; }
        float* valq = (float*)(SM + r * 1024);   // reuse xs region (dead)
        for (int d = 0; d < 256; ++d) {
            int vv = lshI[d * 16 + r];
            int bin = (vv + 8) >> 1;
            int j = cw[bin]++;
            valq[j] = __fadd_rn((float)vv, pe_over[d]);
        }
        float L0 = 0.f, L1 = 0.f, L2 = 0.f, L3 = 0.f,
              L4 = 0.f, L5 = 0.f, L6 = 0.f, L7 = 0.f;
        for (int i = 0; i < 256; i += 8) {
            L0 = fmaf(valq[i + 0], c_f[i + 0], L0);
            L1 = fmaf(valq[i + 1], c_f[i + 1], L1);
            L2 = fmaf(valq[i + 2], c_f[i + 2], L2);
            L3 = fmaf(valq[i + 3], c_f[i + 3], L3);
            L4 = fmaf(valq[i + 4], c_f[i + 4], L4);
            L5 = fmaf(valq[i + 5], c_f[i + 5], L5);
            L6 = fmaf(valq[i + 6], c_f[i + 6], L6);
            L7 = fmaf(valq[i + 7], c_f[i + 7], L7);
        }
        const float h0 = __fadd_rn(L0, L4);
        const float h1 = __fadd_rn(L1, L5);
        const float h2 = __fadd_rn(L2, L6);
        const float h3 = __fadd_rn(L3, L7);
        simv[rowbase + r] = __fadd_rn(__fadd_rn(h0, h2), __fadd_rn(h1, h3));
    }
}

// ---------------- K2: stable rank -> order ----------------
__global__ __launch_bounds__(256)
void k2_rank(const float* __restrict__ simv, int* __restrict__ order)
{
    __shared__ float s_l[4096];
    const int b = blockIdx.x >> 4;
    const int chunk = blockIdx.x & 15;
    const float* S = simv + (long)b * 4096;
    for (int i = threadIdx.x; i < 4096; i += 256) s_l[i] = S[i];
    __syncthreads();
    const int n = chunk * 256 + threadIdx.x;
    const float key = s_l[n];
    int cnt = 0;
    for (int m = 0; m < 4096; ++m) {
        float sm = s_l[m];
        cnt += (sm < key) ? 1 : ((sm == key && m < n) ? 1 : 0);
    }
    order[(long)b * 4096 + cnt] = n;
}

// ---------------- K3: value GEMM on gathered rows ----------------
__global__ __launch_bounds__(256, 2)
void k3_value(const float* __restrict__ z, const int* __restrict__ order,
              const float* __restrict__ Wv, const float* __restrict__ bv,
              float* __restrict__ v)
{
    __shared__ float zT[256 * XS3];
    __shared__ int sh_ord[TN3];
    const int tid = threadIdx.x;
    const long rowbase = (long)blockIdx.x * TN3;
    const long bbase = (rowbase >> 12) << 12;
    if (tid < TN3) sh_ord[tid] = order[rowbase + tid];
    __syncthreads();
    #pragma unroll
    for (int r = 0; r < TN3; ++r)
        zT[tid * XS3 + r] = z[(bbase + sh_ord[r]) * 256 + tid];
    float acc[TN3];
    #pragma unroll
    for (int r = 0; r < TN3; ++r) acc[r] = 0.0f;
    __syncthreads();
    const float* wc = Wv + tid;
    #pragma unroll 2
    for (int k = 0; k < 256; ++k) {
        float w = wc[k * 256];
        const float* zk = &zT[k * XS3];
        #pragma unroll
        for (int r4 = 0; r4 < TN3; r4 += 4) {
            float4 zv = *reinterpret_cast<const float4*>(zk + r4);
            acc[r4 + 0] = fmaf(zv.x, w, acc[r4 + 0]);
            acc[r4 + 1] = fmaf(zv.y, w, acc[r4 + 1]);
            acc[r4 + 2] = fmaf(zv.z, w, acc[r4 + 2]);
            acc[r4 + 3] = fmaf(zv.w, w, acc[r4 + 3]);
        }
    }
    const float bias = bv[tid];
    #pragma unroll
    for (int r = 0; r < TN3; ++r)
        v[(rowbase + r) * 256 + tid] = fmaxf(acc[r] + bias, 0.0f);
}

// ---------------- K4: windowed attention + residual + LayerNorm ----------------
__global__ __launch_bounds__(256)
void k4_attn_ln(const float* __restrict__ z, const float* __restrict__ v,
                const int* __restrict__ order, const float* __restrict__ x,
                const float* __restrict__ gamma, const float* __restrict__ beta,
                float* __restrict__ out)
{
    const int tid = threadIdx.x;
    const int wv = tid >> 6, lane = tid & 63;
    const long row = (long)blockIdx.x * 4 + wv;
    const int n = (int)(row & 4095);
    const long bbase = row - n;
    int start = n - 4;
    start = start < 0 ? 0 : start;
    start = start > (Nc - 9) ? (Nc - 9) : start;
    const int d0 = lane * 4;

    const int srcq = order[bbase + n];
    float4 q4 = *reinterpret_cast<const float4*>(&z[(bbase + srcq) * 256 + d0]);

    float t[9];
    #pragma unroll
    for (int w = 0; w < 9; ++w) {
        int srcm = order[bbase + start + w];
        float4 kv = *reinterpret_cast<const float4*>(&z[(bbase + srcm) * 256 + d0]);
        float p = q4.x * kv.x + q4.y * kv.y + q4.z * kv.z + q4.w * kv.w;
        #pragma unroll
        for (int off = 32; off > 0; off >>= 1) p += __shfl_xor(p, off);
        t[w] = p * 0.0625f;
    }
    float mx = t[0];
    #pragma unroll
    for (int w = 1; w < 9; ++w) mx = fmaxf(mx, t[w]);
    float pw[9], psum = 0.0f;
    #pragma unroll
    for (int w = 0; w < 9; ++w) { pw[w] = expf(t[w] - mx); psum += pw[w]; }
    const float pinv = 1.0f / psum;

    float4 a = make_float4(0.f, 0.f, 0.f, 0.f);
    #pragma unroll
    for (int w = 0; w < 9; ++w) {
        float4 vv = *reinterpret_cast<const float4*>(&v[(bbase + start + w) * 256 + d0]);
        float s = pw[w] * pinv;
        a.x = fmaf(vv.x, s, a.x);
        a.y = fmaf(vv.y, s, a.y);
        a.z = fmaf(vv.z, s, a.z);
        a.w = fmaf(vv.w, s, a.w);
    }
    float4 xv = *reinterpret_cast<const float4*>(&x[(bbase + n) * 256 + d0]);
    float4 y = make_float4(a.x + xv.x, a.y + xv.y, a.z + xv.z, a.w + xv.w);

    float s1 = y.x + y.y + y.z + y.w;
    float s2 = y.x * y.x + y.y * y.y + y.z * y.z + y.w * y.w;
    #pragma unroll
    for (int off = 32; off > 0; off >>= 1) {
        s1 += __shfl_xor(s1, off);
        s2 += __shfl_xor(s2, off);
    }
    const float mu = s1 * (1.0f / 256.0f);
    const float var = s2 * (1.0f / 256.0f) - mu * mu;
    const float istd = 1.0f / sqrtf(var + 0.001f);

    float4 g4 = *reinterpret_cast<const float4*>(&gamma[d0]);
    float4 b4 = *reinterpret_cast<const float4*>(&beta[d0]);
    float4 o;
    o.x = (y.x - mu) * istd * g4.x + b4.x;
    o.y = (y.y - mu) * istd * g4.y + b4.y;
    o.z = (y.z - mu) * istd * g4.z + b4.z;
    o.w = (y.w - mu) * istd * g4.w + b4.w;
    *reinterpret_cast<float4*>(&out[row * 256 + d0]) = o;
}

extern "C" void kernel_launch(void* const* d_in, const int* in_sizes, int n_in,
                              void* d_out, int out_size, void* d_ws, size_t ws_size,
                              hipStream_t stream)
{
    const float* x  = (const float*)d_in[0];
    const float* Wh = (const float*)d_in[1];
    const float* bh = (const float*)d_in[2];
    const float* Wd = (const float*)d_in[3];
    const float* bd = (const float*)d_in[4];
    const float* Wv = (const float*)d_in[5];
    const float* bv = (const float*)d_in[6];
    const float* g  = (const float*)d_in[7];
    const float* be = (const float*)d_in[8];
    float* out = (float*)d_out;

    char* ws = (char*)d_ws;
    float*          z     = (float*)ws;                       // 33554432 B
    float*          v     = (float*)(ws + 33554432);          // 33554432 B
    float*          simv  = (float*)(ws + 67108864);          // 131072 B
    int*            order = (int*)(ws + 67239936);            // 131072 B
    unsigned short* WdT   = (unsigned short*)(ws + 67371008); // 1048576 B
    unsigned short* WhH   = (unsigned short*)(ws + 68419584); // 1048576 B
    unsigned short* WhL   = (unsigned short*)(ws + 69468160); // 1048576 B

    const int rows = Bc * Nc;                                 // 32768
    k0_wdt<<<dim3(128), dim3(256), 0, stream>>>(Wd, WdT);
    k0_whsplit<<<dim3(128), dim3(256), 0, stream>>>(Wh, WhH, WhL);
    k1_head_down<<<dim3(rows / TN), dim3(256), 0, stream>>>(x, Wh, bh, WhH, WhL, WdT, bd, z, simv);
    k2_rank<<<dim3(Bc * 16), dim3(256), 0, stream>>>(simv, order);
    k3_value<<<dim3(rows / TN3), dim3(256), 0, stream>>>(z, order, Wv, bv, v);
    k4_attn_ln<<<dim3(rows / 4), dim3(256), 0, stream>>>(z, v, order, x, g, be, out);
}

// Round 12
// 971.556 us; speedup vs baseline: 1.1806x; 1.1806x over previous
//
#include <hip/hip_runtime.h>

constexpr int Bc = 8, Nc = 4096;
constexpr int TN = 16;    // rows per workgroup in K1
constexpr int TN3 = 32;   // rows per workgroup in K3
constexpr int XS3 = 36;

using short8 = __attribute__((ext_vector_type(8))) short;
using f32x4  = __attribute__((ext_vector_type(4))) float;

static __device__ __forceinline__ unsigned short f2bf(float f) {
    unsigned u = __float_as_uint(f);
    u += 0x7fffu + ((u >> 16) & 1u);     // RNE
    return (unsigned short)(u >> 16);
}
// XOR-swizzled byte offset for a [16][256] ushort LDS plane (16B-access safe)
static __device__ __forceinline__ int swz(int r, int k) {
    return (r << 9) + ((k << 1) ^ ((r & 7) << 4));
}

// ---------------- K0a: Wd [h][d][e] f32 -> WdT [h][e][d] bf16 ----------------
__global__ __launch_bounds__(256)
void k0_wdt(const float* __restrict__ Wd, unsigned short* __restrict__ WdT)
{
    __shared__ float tile[64][65];
    const int h  = blockIdx.x >> 4;
    const int t  = blockIdx.x & 15;
    const int kb = (t >> 2) * 64, eb = (t & 3) * 64;
    const int tid = threadIdx.x;
    {
        const int krow = tid >> 2, ec = (tid & 3) * 16;
        const float* src = Wd + h * 65536 + (kb + krow) * 256 + eb + ec;
        #pragma unroll
        for (int i = 0; i < 4; ++i) {
            float4 v = *reinterpret_cast<const float4*>(src + i * 4);
            tile[krow][ec + i * 4 + 0] = v.x;
            tile[krow][ec + i * 4 + 1] = v.y;
            tile[krow][ec + i * 4 + 2] = v.z;
            tile[krow][ec + i * 4 + 3] = v.w;
        }
    }
    __syncthreads();
    {
        const int erow = tid >> 2, dc = (tid & 3) * 16;
        unsigned short o[16];
        #pragma unroll
        for (int i = 0; i < 16; ++i) o[i] = f2bf(tile[dc + i][erow]);
        unsigned short* dst = WdT + h * 65536 + (eb + erow) * 256 + kb + dc;
        *reinterpret_cast<short8*>(dst)     = *reinterpret_cast<short8*>(&o[0]);
        *reinterpret_cast<short8*>(dst + 8) = *reinterpret_cast<short8*>(&o[8]);
    }
}

// ---------------- K0b: Wh [k][h][e] f32 -> WhH [h][e][k] bf16 ----------------
__global__ __launch_bounds__(256)
void k0_wht(const float* __restrict__ Wh, unsigned short* __restrict__ WhH)
{
    __shared__ float tile[64][65];
    const int h  = blockIdx.x >> 4;
    const int t  = blockIdx.x & 15;
    const int kb = (t >> 2) * 64, eb = (t & 3) * 64;
    const int tid = threadIdx.x;
    {
        const int krow = tid >> 2, ec = (tid & 3) * 16;
        const float* src = Wh + (kb + krow) * 2048 + h * 256 + eb + ec;
        #pragma unroll
        for (int i = 0; i < 4; ++i) {
            float4 v = *reinterpret_cast<const float4*>(src + i * 4);
            tile[krow][ec + i * 4 + 0] = v.x;
            tile[krow][ec + i * 4 + 1] = v.y;
            tile[krow][ec + i * 4 + 2] = v.z;
            tile[krow][ec + i * 4 + 3] = v.w;
        }
    }
    __syncthreads();
    {
        const int erow = tid >> 2, dc = (tid & 3) * 16;
        unsigned short o[16];
        #pragma unroll
        for (int i = 0; i < 16; ++i) o[i] = f2bf(tile[dc + i][erow]);
        unsigned short* dst = WhH + (long)h * 65536 + (eb + erow) * 256 + kb + dc;
        *reinterpret_cast<short8*>(dst)     = *reinterpret_cast<short8*>(&o[0]);
        *reinterpret_cast<short8*>(dst + 8) = *reinterpret_cast<short8*>(&o[8]);
    }
}

// LDS layout (bytes) for K1
#define XSH_OFF 0        // [16][256] ushort swizzled (x bf16-hi)
#define QTB_OFF 8192     // [16][256] ushort swizzled (q bf16, per h)
#define LSH_OFF 16384    // int[256][16]  (lsh[e][r])
#define PE_OFF  32768    // float[256]
#define CF_OFF  33792    // float[256]
#define CNT_OFF 34816    // int[16][16]
#define FCN_OFF 35840    // int
#define FLS_OFF 35856    // int[1024]
#define FLS_CAP 1024
#define GUARD   0.012f

// ---------------- K1: bf16-MFMA head GEMM (sign-guarded) + MFMA down GEMM ----------------
__global__ __launch_bounds__(256, 4)
void k1_head_down(const float* __restrict__ x,
                  const float* __restrict__ Wh, const float* __restrict__ bh,
                  const unsigned short* __restrict__ WhH,
                  const unsigned short* __restrict__ WdT, const float* __restrict__ bd,
                  float* __restrict__ z, float* __restrict__ simv)
{
    __shared__ __align__(16) char SM[40192];

    const int tid = threadIdx.x;
    const long rowbase = (long)blockIdx.x * TN;
    const int wavei = tid >> 6, lane = tid & 63;
    const int mrow = lane & 15, kgrp = lane >> 4;
    const int ebase = wavei * 64 + mrow;
    const int kfo = kgrp * 8;

    {   // XLA:CPU twin tables (CR libm via f64-round)
        const int d = tid;
        const float u = -((float)d * 0.00390625f);
        const float freq = (float)pow(10.0, (double)u);
        const float pe = (d & 1) ? (float)sin((double)freq)
                                 : (float)cos((double)freq);
        ((float*)(SM + PE_OFF))[d] = __fdiv_rn(pe, 0.4f);
        ((float*)(SM + CF_OFF))[d] = __fmul_rn(0.4f, (float)pow((double)0.6f, (double)d));
    }
    if (tid == 0) *((int*)(SM + FCN_OFF)) = 0;
    {   // x -> bf16-hi LDS (swizzled)
        const int r = tid >> 4, kc = (tid & 15) * 16;
        const float* src = x + (rowbase + r) * 256 + kc;
        unsigned short oh[16];
        #pragma unroll
        for (int i = 0; i < 16; i += 4) {
            float4 v = *reinterpret_cast<const float4*>(src + i);
            oh[i + 0] = f2bf(v.x); oh[i + 1] = f2bf(v.y);
            oh[i + 2] = f2bf(v.z); oh[i + 3] = f2bf(v.w);
        }
        *reinterpret_cast<short8*>(SM + XSH_OFF + swz(r, kc))     = *reinterpret_cast<short8*>(&oh[0]);
        *reinterpret_cast<short8*>(SM + XSH_OFF + swz(r, kc + 8)) = *reinterpret_cast<short8*>(&oh[8]);
    }

    short8 bufA[4], bufB[4], dbufA[4], dbufB[4];
    #pragma unroll
    for (int nf = 0; nf < 4; ++nf)   // preload h=0, kt=0 head B frags
        bufA[nf] = *reinterpret_cast<const short8*>(&WhH[(ebase + nf * 16) * 256 + kfo]);

    int lshv[16];
    #pragma unroll
    for (int i = 0; i < 16; ++i) lshv[i] = 0;
    f32x4 dacc[4];
    #pragma unroll
    for (int nf = 0; nf < 4; ++nf) dacc[nf] = (f32x4){0.f, 0.f, 0.f, 0.f};

    __syncthreads();

    for (int h = 0; h < 8; ++h) {
        const unsigned short* whh = WhH + ((long)h << 16);
        const unsigned short* wdh = WdT + ((long)h << 16);
        float bias[4];
        #pragma unroll
        for (int nf = 0; nf < 4; ++nf) bias[nf] = bh[(h << 8) + ebase + nf * 16];

        // ---- head GEMM: 1-term bf16 MFMA, double-buffered B prefetch ----
        f32x4 hacc[4];
        #pragma unroll
        for (int nf = 0; nf < 4; ++nf) hacc[nf] = (f32x4){0.f, 0.f, 0.f, 0.f};
        #pragma unroll
        for (int kt = 0; kt < 8; ++kt) {
            const int k0 = kt * 32 + kfo;
            short8 afh = *reinterpret_cast<const short8*>(SM + XSH_OFF + swz(mrow, k0));
            if (kt < 7) {
                #pragma unroll
                for (int nf = 0; nf < 4; ++nf) {
                    short8 v = *reinterpret_cast<const short8*>(
                        &whh[(ebase + nf * 16) * 256 + k0 + 32]);
                    if ((kt & 1) == 0) bufB[nf] = v; else bufA[nf] = v;
                }
            }
            #pragma unroll
            for (int nf = 0; nf < 4; ++nf) {
                short8 b = ((kt & 1) == 0) ? bufA[nf] : bufB[nf];
                hacc[nf] = __builtin_amdgcn_mfma_f32_16x16x32_bf16(afh, b, hacc[nf], 0, 0, 0);
            }
        }
        // prefetch down ks=0 B frags (latency hides under sign/VALU phase)
        #pragma unroll
        for (int nf = 0; nf < 4; ++nf)
            dbufA[nf] = *reinterpret_cast<const short8*>(&wdh[(ebase + nf * 16) * 256 + kfo]);

        // ---- signs / guard-list / qTb ----
        #pragma unroll
        for (int nf = 0; nf < 4; ++nf) {
            const int e = ebase + nf * 16;
            #pragma unroll
            for (int reg = 0; reg < 4; ++reg) {
                const int r = kgrp * 4 + reg;
                const float pre = __fadd_rn(hacc[nf][reg], bias[nf]);
                const int s = (pre > 0.0f) ? 1 : -1;
                lshv[nf * 4 + reg] += s;
                if (fabsf(pre) < GUARD) {
                    int idx = atomicAdd((int*)(SM + FCN_OFF), 1);
                    if (idx < FLS_CAP)
                        ((int*)(SM + FLS_OFF))[idx] =
                            r | (e << 4) | (h << 12) | ((s > 0 ? 1 : 0) << 15);
                }
                *reinterpret_cast<unsigned short*>(SM + QTB_OFF + swz(r, e)) =
                    f2bf(fmaxf(pre, 0.0f));
            }
        }
        __syncthreads();   // qTb ready
        // ---- down GEMM: bf16 MFMA, double-buffered B prefetch ----
        #pragma unroll
        for (int ks = 0; ks < 8; ++ks) {
            const int k0 = ks * 32 + kfo;
            short8 af = *reinterpret_cast<const short8*>(SM + QTB_OFF + swz(mrow, k0));
            if (ks < 7) {
                #pragma unroll
                for (int nf = 0; nf < 4; ++nf) {
                    short8 v = *reinterpret_cast<const short8*>(
                        &wdh[(ebase + nf * 16) * 256 + k0 + 32]);
                    if ((ks & 1) == 0) dbufB[nf] = v; else dbufA[nf] = v;
                }
            }
            if (ks == 4 && h < 7) {   // prefetch next-h head kt=0 (hides before barrier)
                #pragma unroll
                for (int nf = 0; nf < 4; ++nf)
                    bufA[nf] = *reinterpret_cast<const short8*>(
                        &WhH[((long)(h + 1) << 16) + (ebase + nf * 16) * 256 + kfo]);
            }
            #pragma unroll
            for (int nf = 0; nf < 4; ++nf) {
                short8 b = ((ks & 1) == 0) ? dbufA[nf] : dbufB[nf];
                dacc[nf] = __builtin_amdgcn_mfma_f32_16x16x32_bf16(af, b, dacc[nf], 0, 0, 0);
            }
        }
        __syncthreads();   // qTb free for next h
    }
    // ---- epilogue: z = relu(dacc + bd) ----
    #pragma unroll
    for (int nf = 0; nf < 4; ++nf) {
        const int e = ebase + nf * 16;
        const float b = bd[e];
        #pragma unroll
        for (int reg = 0; reg < 4; ++reg) {
            const int m = kgrp * 4 + reg;
            z[(rowbase + m) * 256 + e] = fmaxf(dacc[nf][reg] + b, 0.0f);
        }
    }
    // ---- lsh base write ----
    {
        int* lshI = (int*)(SM + LSH_OFF);
        #pragma unroll
        for (int nf = 0; nf < 4; ++nf) {
            const int e = ebase + nf * 16;
            #pragma unroll
            for (int reg = 0; reg < 4; ++reg)
                lshI[e * 16 + kgrp * 4 + reg] = lshv[nf * 4 + reg];
        }
    }
    __syncthreads();
    // ---- guard: exact ascending-k f32 chain for near-zero preacts ----
    {
        int n = *((int*)(SM + FCN_OFF));
        n = n < FLS_CAP ? n : FLS_CAP;
        for (int i = tid; i < n; i += 256) {
            const int ent = ((int*)(SM + FLS_OFF))[i];
            const int r = ent & 15, e = (ent >> 4) & 255, hh2 = (ent >> 12) & 7;
            const int fs = ((ent >> 15) & 1) ? 1 : -1;
            const float* xr = x + (rowbase + r) * 256;
            const float* wcol = Wh + hh2 * 256 + e;
            float acc = 0.0f;
            for (int k = 0; k < 256; ++k)
                acc = fmaf(xr[k], wcol[k * 2048], acc);
            const float pre = __fadd_rn(acc, bh[hh2 * 256 + e]);
            const int es = (pre > 0.0f) ? 1 : -1;
            if (es != fs)
                atomicAdd(&((int*)(SM + LSH_OFF))[e * 16 + r], es - fs);
        }
    }
    __syncthreads();
    // ---- tail: stable counting sort + simv (bit-exact, r9-verified) ----
    if (tid < TN) {
        const int r = tid;
        const int* lshI = (const int*)(SM + LSH_OFF);
        const float* pe_over = (const float*)(SM + PE_OFF);
        const float* c_f = (const float*)(SM + CF_OFF);
        int* cw = (int*)(SM + CNT_OFF) + r * 16;
        for (int i = 0; i < 9; ++i) cw[i] = 0;
        for (int d = 0; d < 256; ++d) {
            int vv = lshI[d * 16 + r];
            cw[(vv + 8) >> 1] += 1;
        }
        int run = 0;
        for (int bin = 8; bin >= 0; --bin) { int c0 = cw[bin]; cw[bin] = run; run += c0; }
        float* valq = (float*)(SM + r * 1024);   // XSH/QTB region (dead)
        for (int d = 0; d < 256; ++d) {
            int vv = lshI[d * 16 + r];
            int bin = (vv + 8) >> 1;
            int j = cw[bin]++;
            valq[j] = __fadd_rn((float)vv, pe_over[d]);
        }
        float L0 = 0.f, L1 = 0.f, L2 = 0.f, L3 = 0.f,
              L4 = 0.f, L5 = 0.f, L6 = 0.f, L7 = 0.f;
        for (int i = 0; i < 256; i += 8) {
            L0 = fmaf(valq[i + 0], c_f[i + 0], L0);
            L1 = fmaf(valq[i + 1], c_f[i + 1], L1);
            L2 = fmaf(valq[i + 2], c_f[i + 2], L2);
            L3 = fmaf(valq[i + 3], c_f[i + 3], L3);
            L4 = fmaf(valq[i + 4], c_f[i + 4], L4);
            L5 = fmaf(valq[i + 5], c_f[i + 5], L5);
            L6 = fmaf(valq[i + 6], c_f[i + 6], L6);
            L7 = fmaf(valq[i + 7], c_f[i + 7], L7);
        }
        const float h0 = __fadd_rn(L0, L4);
        const float h1 = __fadd_rn(L1, L5);
        const float h2 = __fadd_rn(L2, L6);
        const float h3 = __fadd_rn(L3, L7);
        simv[rowbase + r] = __fadd_rn(__fadd_rn(h0, h2), __fadd_rn(h1, h3));
    }
}

// ---------------- K2: stable rank -> order ----------------
__global__ __launch_bounds__(256)
void k2_rank(const float* __restrict__ simv, int* __restrict__ order)
{
    __shared__ float s_l[4096];
    const int b = blockIdx.x >> 4;
    const int chunk = blockIdx.x & 15;
    const float* S = simv + (long)b * 4096;
    for (int i = threadIdx.x; i < 4096; i += 256) s_l[i] = S[i];
    __syncthreads();
    const int n = chunk * 256 + threadIdx.x;
    const float key = s_l[n];
    int cnt = 0;
    for (int m = 0; m < 4096; ++m) {
        float sm = s_l[m];
        cnt += (sm < key) ? 1 : ((sm == key && m < n) ? 1 : 0);
    }
    order[(long)b * 4096 + cnt] = n;
}

// ---------------- K3: value GEMM on gathered rows ----------------
__global__ __launch_bounds__(256, 2)
void k3_value(const float* __restrict__ z, const int* __restrict__ order,
              const float* __restrict__ Wv, const float* __restrict__ bv,
              float* __restrict__ v)
{
    __shared__ float zT[256 * XS3];
    __shared__ int sh_ord[TN3];
    const int tid = threadIdx.x;
    const long rowbase = (long)blockIdx.x * TN3;
    const long bbase = (rowbase >> 12) << 12;
    if (tid < TN3) sh_ord[tid] = order[rowbase + tid];
    __syncthreads();
    #pragma unroll
    for (int r = 0; r < TN3; ++r)
        zT[tid * XS3 + r] = z[(bbase + sh_ord[r]) * 256 + tid];
    float acc[TN3];
    #pragma unroll
    for (int r = 0; r < TN3; ++r) acc[r] = 0.0f;
    __syncthreads();
    const float* wc = Wv + tid;
    #pragma unroll 2
    for (int k = 0; k < 256; ++k) {
        float w = wc[k * 256];
        const float* zk = &zT[k * XS3];
        #pragma unroll
        for (int r4 = 0; r4 < TN3; r4 += 4) {
            float4 zv = *reinterpret_cast<const float4*>(zk + r4);
            acc[r4 + 0] = fmaf(zv.x, w, acc[r4 + 0]);
            acc[r4 + 1] = fmaf(zv.y, w, acc[r4 + 1]);
            acc[r4 + 2] = fmaf(zv.z, w, acc[r4 + 2]);
            acc[r4 + 3] = fmaf(zv.w, w, acc[r4 + 3]);
        }
    }
    const float bias = bv[tid];
    #pragma unroll
    for (int r = 0; r < TN3; ++r)
        v[(rowbase + r) * 256 + tid] = fmaxf(acc[r] + bias, 0.0f);
}

// ---------------- K4: windowed attention + residual + LayerNorm ----------------
__global__ __launch_bounds__(256)
void k4_attn_ln(const float* __restrict__ z, const float* __restrict__ v,
                const int* __restrict__ order, const float* __restrict__ x,
                const float* __restrict__ gamma, const float* __restrict__ beta,
                float* __restrict__ out)
{
    const int tid = threadIdx.x;
    const int wv = tid >> 6, lane = tid & 63;
    const long row = (long)blockIdx.x * 4 + wv;
    const int n = (int)(row & 4095);
    const long bbase = row - n;
    int start = n - 4;
    start = start < 0 ? 0 : start;
    start = start > (Nc - 9) ? (Nc - 9) : start;
    const int d0 = lane * 4;

    const int srcq = order[bbase + n];
    float4 q4 = *reinterpret_cast<const float4*>(&z[(bbase + srcq) * 256 + d0]);

    float t[9];
    #pragma unroll
    for (int w = 0; w < 9; ++w) {
        int srcm = order[bbase + start + w];
        float4 kv = *reinterpret_cast<const float4*>(&z[(bbase + srcm) * 256 + d0]);
        float p = q4.x * kv.x + q4.y * kv.y + q4.z * kv.z + q4.w * kv.w;
        #pragma unroll
        for (int off = 32; off > 0; off >>= 1) p += __shfl_xor(p, off);
        t[w] = p * 0.0625f;
    }
    float mx = t[0];
    #pragma unroll
    for (int w = 1; w < 9; ++w) mx = fmaxf(mx, t[w]);
    float pw[9], psum = 0.0f;
    #pragma unroll
    for (int w = 0; w < 9; ++w) { pw[w] = expf(t[w] - mx); psum += pw[w]; }
    const float pinv = 1.0f / psum;

    float4 a = make_float4(0.f, 0.f, 0.f, 0.f);
    #pragma unroll
    for (int w = 0; w < 9; ++w) {
        float4 vv = *reinterpret_cast<const float4*>(&v[(bbase + start + w) * 256 + d0]);
        float s = pw[w] * pinv;
        a.x = fmaf(vv.x, s, a.x);
        a.y = fmaf(vv.y, s, a.y);
        a.z = fmaf(vv.z, s, a.z);
        a.w = fmaf(vv.w, s, a.w);
    }
    float4 xv = *reinterpret_cast<const float4*>(&x[(bbase + n) * 256 + d0]);
    float4 y = make_float4(a.x + xv.x, a.y + xv.y, a.z + xv.z, a.w + xv.w);

    float s1 = y.x + y.y + y.z + y.w;
    float s2 = y.x * y.x + y.y * y.y + y.z * y.z + y.w * y.w;
    #pragma unroll
    for (int off = 32; off > 0; off >>= 1) {
        s1 += __shfl_xor(s1, off);
        s2 += __shfl_xor(s2, off);
    }
    const float mu = s1 * (1.0f / 256.0f);
    const float var = s2 * (1.0f / 256.0f) - mu * mu;
    const float istd = 1.0f / sqrtf(var + 0.001f);

    float4 g4 = *reinterpret_cast<const float4*>(&gamma[d0]);
    float4 b4 = *reinterpret_cast<const float4*>(&beta[d0]);
    float4 o;
    o.x = (y.x - mu) * istd * g4.x + b4.x;
    o.y = (y.y - mu) * istd * g4.y + b4.y;
    o.z = (y.z - mu) * istd * g4.z + b4.z;
    o.w = (y.w - mu) * istd * g4.w + b4.w;
    *reinterpret_cast<float4*>(&out[row * 256 + d0]) = o;
}

extern "C" void kernel_launch(void* const* d_in, const int* in_sizes, int n_in,
                              void* d_out, int out_size, void* d_ws, size_t ws_size,
                              hipStream_t stream)
{
    const float* x  = (const float*)d_in[0];
    const float* Wh = (const float*)d_in[1];
    const float* bh = (const float*)d_in[2];
    const float* Wd = (const float*)d_in[3];
    const float* bd = (const float*)d_in[4];
    const float* Wv = (const float*)d_in[5];
    const float* bv = (const float*)d_in[6];
    const float* g  = (const float*)d_in[7];
    const float* be = (const float*)d_in[8];
    float* out = (float*)d_out;

    char* ws = (char*)d_ws;
    float*          z     = (float*)ws;                       // 33554432 B
    float*          v     = (float*)(ws + 33554432);          // 33554432 B
    float*          simv  = (float*)(ws + 67108864);          // 131072 B
    int*            order = (int*)(ws + 67239936);            // 131072 B
    unsigned short* WdT   = (unsigned short*)(ws + 67371008); // 1048576 B
    unsigned short* WhH   = (unsigned short*)(ws + 68419584); // 1048576 B

    const int rows = Bc * Nc;                                 // 32768
    k0_wdt<<<dim3(128), dim3(256), 0, stream>>>(Wd, WdT);
    k0_wht<<<dim3(128), dim3(256), 0, stream>>>(Wh, WhH);
    k1_head_down<<<dim3(rows / TN), dim3(256), 0, stream>>>(x, Wh, bh, WhH, WdT, bd, z, simv);
    k2_rank<<<dim3(Bc * 16), dim3(256), 0, stream>>>(simv, order);
    k3_value<<<dim3(rows / TN3), dim3(256), 0, stream>>>(z, order, Wv, bv, v);
    k4_attn_ln<<<dim3(rows / 4), dim3(256), 0, stream>>>(z, v, order, x, g, be, out);
}

// Round 13
// 916.914 us; speedup vs baseline: 1.2509x; 1.0596x over previous
//
#include <hip/hip_runtime.h>

constexpr int Bc = 8, Nc = 4096;
constexpr int TN = 16;    // rows per workgroup in K1
constexpr int TN3 = 32;   // rows per workgroup in K3
constexpr int XS3 = 36;

using short8 = __attribute__((ext_vector_type(8))) short;
using f32x4  = __attribute__((ext_vector_type(4))) float;

static __device__ __forceinline__ unsigned short f2bf(float f) {
    unsigned u = __float_as_uint(f);
    u += 0x7fffu + ((u >> 16) & 1u);     // RNE
    return (unsigned short)(u >> 16);
}
// XOR-swizzled byte offset for a [16][256] ushort LDS plane (16B-access safe)
static __device__ __forceinline__ int swz(int r, int k) {
    return (r << 9) + ((k << 1) ^ ((r & 7) << 4));
}

// ---------------- K0a: Wd [h][d][e] f32 -> WdT [h][e][d] bf16 ----------------
__global__ __launch_bounds__(256)
void k0_wdt(const float* __restrict__ Wd, unsigned short* __restrict__ WdT)
{
    __shared__ float tile[64][65];
    const int h  = blockIdx.x >> 4;
    const int t  = blockIdx.x & 15;
    const int kb = (t >> 2) * 64, eb = (t & 3) * 64;
    const int tid = threadIdx.x;
    {
        const int krow = tid >> 2, ec = (tid & 3) * 16;
        const float* src = Wd + h * 65536 + (kb + krow) * 256 + eb + ec;
        #pragma unroll
        for (int i = 0; i < 4; ++i) {
            float4 v = *reinterpret_cast<const float4*>(src + i * 4);
            tile[krow][ec + i * 4 + 0] = v.x;
            tile[krow][ec + i * 4 + 1] = v.y;
            tile[krow][ec + i * 4 + 2] = v.z;
            tile[krow][ec + i * 4 + 3] = v.w;
        }
    }
    __syncthreads();
    {
        const int erow = tid >> 2, dc = (tid & 3) * 16;
        unsigned short o[16];
        #pragma unroll
        for (int i = 0; i < 16; ++i) o[i] = f2bf(tile[dc + i][erow]);
        unsigned short* dst = WdT + h * 65536 + (eb + erow) * 256 + kb + dc;
        *reinterpret_cast<short8*>(dst)     = *reinterpret_cast<short8*>(&o[0]);
        *reinterpret_cast<short8*>(dst + 8) = *reinterpret_cast<short8*>(&o[8]);
    }
}

// ---------------- K0b: Wh [k][h][e] f32 -> WhH bf16 [h][e][k] + WhT f32 [h][e][k] ----------------
__global__ __launch_bounds__(256)
void k0_wht(const float* __restrict__ Wh, unsigned short* __restrict__ WhH,
            float* __restrict__ WhT)
{
    __shared__ float tile[64][65];
    const int h  = blockIdx.x >> 4;
    const int t  = blockIdx.x & 15;
    const int kb = (t >> 2) * 64, eb = (t & 3) * 64;
    const int tid = threadIdx.x;
    {
        const int krow = tid >> 2, ec = (tid & 3) * 16;
        const float* src = Wh + (kb + krow) * 2048 + h * 256 + eb + ec;
        #pragma unroll
        for (int i = 0; i < 4; ++i) {
            float4 v = *reinterpret_cast<const float4*>(src + i * 4);
            tile[krow][ec + i * 4 + 0] = v.x;
            tile[krow][ec + i * 4 + 1] = v.y;
            tile[krow][ec + i * 4 + 2] = v.z;
            tile[krow][ec + i * 4 + 3] = v.w;
        }
    }
    __syncthreads();
    {
        const int erow = tid >> 2, dc = (tid & 3) * 16;
        unsigned short o[16];
        float of[16];
        #pragma unroll
        for (int i = 0; i < 16; ++i) {
            of[i] = tile[dc + i][erow];
            o[i] = f2bf(of[i]);
        }
        const long base = (long)h * 65536 + (eb + erow) * 256 + kb + dc;
        *reinterpret_cast<short8*>(WhH + base)     = *reinterpret_cast<short8*>(&o[0]);
        *reinterpret_cast<short8*>(WhH + base + 8) = *reinterpret_cast<short8*>(&o[8]);
        #pragma unroll
        for (int i = 0; i < 16; i += 4)
            *reinterpret_cast<float4*>(WhT + base + i) = *reinterpret_cast<const float4*>(&of[i]);
    }
}

// LDS layout (bytes) for K1
#define XSH_OFF 0        // [16][256] ushort swizzled (x bf16-hi)
#define QTB_OFF 8192     // [16][256] ushort swizzled (q bf16, per h)
#define LSH_OFF 16384    // int[256][16]  (lsh[e][r])
#define PE_OFF  32768    // float[256]
#define CF_OFF  33792    // float[256]
#define CNT_OFF 34816    // int[16][16]
#define FCN_OFF 35840    // int
#define FLS_OFF 35856    // int[1024]
#define FLS_CAP 1024
#define GUARD   0.012f

// ---------------- K1: bf16-MFMA head GEMM (sign-guarded) + MFMA down GEMM, 2-deep prefetch ----------------
__global__ __launch_bounds__(256, 2)
void k1_head_down(const float* __restrict__ x,
                  const float* __restrict__ bh,
                  const float* __restrict__ WhT,
                  const unsigned short* __restrict__ WhH,
                  const unsigned short* __restrict__ WdT, const float* __restrict__ bd,
                  float* __restrict__ z, float* __restrict__ simv)
{
    __shared__ __align__(16) char SM[40192];

    const int tid = threadIdx.x;
    const long rowbase = (long)blockIdx.x * TN;
    const int wavei = tid >> 6, lane = tid & 63;
    const int mrow = lane & 15, kgrp = lane >> 4;
    const int ebase = wavei * 64 + mrow;
    const int kfo = kgrp * 8;

    {   // XLA:CPU twin tables (CR libm via f64-round)
        const int d = tid;
        const float u = -((float)d * 0.00390625f);
        const float freq = (float)pow(10.0, (double)u);
        const float pe = (d & 1) ? (float)sin((double)freq)
                                 : (float)cos((double)freq);
        ((float*)(SM + PE_OFF))[d] = __fdiv_rn(pe, 0.4f);
        ((float*)(SM + CF_OFF))[d] = __fmul_rn(0.4f, (float)pow((double)0.6f, (double)d));
    }
    if (tid == 0) *((int*)(SM + FCN_OFF)) = 0;
    {   // x -> bf16-hi LDS (swizzled)
        const int r = tid >> 4, kc = (tid & 15) * 16;
        const float* src = x + (rowbase + r) * 256 + kc;
        unsigned short oh[16];
        #pragma unroll
        for (int i = 0; i < 16; i += 4) {
            float4 v = *reinterpret_cast<const float4*>(src + i);
            oh[i + 0] = f2bf(v.x); oh[i + 1] = f2bf(v.y);
            oh[i + 2] = f2bf(v.z); oh[i + 3] = f2bf(v.w);
        }
        *reinterpret_cast<short8*>(SM + XSH_OFF + swz(r, kc))     = *reinterpret_cast<short8*>(&oh[0]);
        *reinterpret_cast<short8*>(SM + XSH_OFF + swz(r, kc + 8)) = *reinterpret_cast<short8*>(&oh[8]);
    }

    short8 hb[3][4], db[3][4];            // 2-deep rings (statically indexed)
    #pragma unroll
    for (int nf = 0; nf < 4; ++nf) {      // preload h=0 kt=0,1
        hb[0][nf] = *reinterpret_cast<const short8*>(&WhH[(ebase + nf * 16) * 256 + kfo]);
        hb[1][nf] = *reinterpret_cast<const short8*>(&WhH[(ebase + nf * 16) * 256 + 32 + kfo]);
    }

    unsigned lshp0 = 0, lshp1 = 0;        // nibble-packed positive counts (16 cells)
    f32x4 dacc[4];
    #pragma unroll
    for (int nf = 0; nf < 4; ++nf) dacc[nf] = (f32x4){0.f, 0.f, 0.f, 0.f};

    __syncthreads();

    for (int h = 0; h < 8; ++h) {
        const unsigned short* whh = WhH + ((long)h << 16);
        const unsigned short* wdh = WdT + ((long)h << 16);
        float bias[4];
        #pragma unroll
        for (int nf = 0; nf < 4; ++nf) bias[nf] = bh[(h << 8) + ebase + nf * 16];

        // ---- head GEMM: bf16 MFMA, 2-deep ring prefetch ----
        f32x4 hacc[4];
        #pragma unroll
        for (int nf = 0; nf < 4; ++nf) hacc[nf] = (f32x4){0.f, 0.f, 0.f, 0.f};
        #pragma unroll
        for (int kt = 0; kt < 8; ++kt) {
            const int k0 = kt * 32 + kfo;
            short8 afh = *reinterpret_cast<const short8*>(SM + XSH_OFF + swz(mrow, k0));
            if (kt < 6) {
                #pragma unroll
                for (int nf = 0; nf < 4; ++nf)
                    hb[(kt + 2) % 3][nf] = *reinterpret_cast<const short8*>(
                        &whh[(ebase + nf * 16) * 256 + k0 + 64]);
            }
            if (kt == 6) {     // prefetch down ks=0 (independent of qtb)
                #pragma unroll
                for (int nf = 0; nf < 4; ++nf)
                    db[0][nf] = *reinterpret_cast<const short8*>(
                        &wdh[(ebase + nf * 16) * 256 + kfo]);
            }
            if (kt == 7) {     // prefetch down ks=1
                #pragma unroll
                for (int nf = 0; nf < 4; ++nf)
                    db[1][nf] = *reinterpret_cast<const short8*>(
                        &wdh[(ebase + nf * 16) * 256 + 32 + kfo]);
            }
            #pragma unroll
            for (int nf = 0; nf < 4; ++nf)
                hacc[nf] = __builtin_amdgcn_mfma_f32_16x16x32_bf16(afh, hb[kt % 3][nf], hacc[nf], 0, 0, 0);
        }
        // ---- signs / guard-list / qTb ----
        #pragma unroll
        for (int nf = 0; nf < 4; ++nf) {
            const int e = ebase + nf * 16;
            #pragma unroll
            for (int reg = 0; reg < 4; ++reg) {
                const int r = kgrp * 4 + reg;
                const float pre = __fadd_rn(hacc[nf][reg], bias[nf]);
                const unsigned pos = (pre > 0.0f) ? 1u : 0u;
                const int j = nf * 4 + reg;
                if (j < 8) lshp0 += pos << (4 * j); else lshp1 += pos << (4 * (j - 8));
                if (fabsf(pre) < GUARD) {
                    int idx = atomicAdd((int*)(SM + FCN_OFF), 1);
                    if (idx < FLS_CAP)
                        ((int*)(SM + FLS_OFF))[idx] =
                            r | (e << 4) | (h << 12) | ((int)pos << 15);
                }
                *reinterpret_cast<unsigned short*>(SM + QTB_OFF + swz(r, e)) =
                    f2bf(fmaxf(pre, 0.0f));
            }
        }
        __syncthreads();   // qTb ready
        // ---- down GEMM: bf16 MFMA, 2-deep ring prefetch ----
        #pragma unroll
        for (int ks = 0; ks < 8; ++ks) {
            const int k0 = ks * 32 + kfo;
            short8 af = *reinterpret_cast<const short8*>(SM + QTB_OFF + swz(mrow, k0));
            if (ks < 6) {
                #pragma unroll
                for (int nf = 0; nf < 4; ++nf)
                    db[(ks + 2) % 3][nf] = *reinterpret_cast<const short8*>(
                        &wdh[(ebase + nf * 16) * 256 + k0 + 64]);
            }
            if (ks == 6 && h < 7) {   // prefetch next-h head kt=0
                #pragma unroll
                for (int nf = 0; nf < 4; ++nf)
                    hb[0][nf] = *reinterpret_cast<const short8*>(
                        &WhH[((long)(h + 1) << 16) + (ebase + nf * 16) * 256 + kfo]);
            }
            if (ks == 7 && h < 7) {   // prefetch next-h head kt=1
                #pragma unroll
                for (int nf = 0; nf < 4; ++nf)
                    hb[1][nf] = *reinterpret_cast<const short8*>(
                        &WhH[((long)(h + 1) << 16) + (ebase + nf * 16) * 256 + 32 + kfo]);
            }
            #pragma unroll
            for (int nf = 0; nf < 4; ++nf)
                dacc[nf] = __builtin_amdgcn_mfma_f32_16x16x32_bf16(af, db[ks % 3][nf], dacc[nf], 0, 0, 0);
        }
        __syncthreads();   // qTb free for next h
    }
    // ---- epilogue: z = relu(dacc + bd) ----
    #pragma unroll
    for (int nf = 0; nf < 4; ++nf) {
        const int e = ebase + nf * 16;
        const float b = bd[e];
        #pragma unroll
        for (int reg = 0; reg < 4; ++reg) {
            const int m = kgrp * 4 + reg;
            z[(rowbase + m) * 256 + e] = fmaxf(dacc[nf][reg] + b, 0.0f);
        }
    }
    // ---- lsh base write (decode packed counts: lsh = 2p - 8) ----
    {
        int* lshI = (int*)(SM + LSH_OFF);
        #pragma unroll
        for (int nf = 0; nf < 4; ++nf) {
            const int e = ebase + nf * 16;
            #pragma unroll
            for (int reg = 0; reg < 4; ++reg) {
                const int j = nf * 4 + reg;
                const unsigned p = ((j < 8) ? (lshp0 >> (4 * j)) : (lshp1 >> (4 * (j - 8)))) & 15u;
                lshI[e * 16 + kgrp * 4 + reg] = 2 * (int)p - 8;
            }
        }
    }
    __syncthreads();
    // ---- guard: exact ascending-k f32 chain (contiguous WhT reads) ----
    {
        int n = *((int*)(SM + FCN_OFF));
        n = n < FLS_CAP ? n : FLS_CAP;
        for (int i = tid; i < n; i += 256) {
            const int ent = ((int*)(SM + FLS_OFF))[i];
            const int r = ent & 15, e = (ent >> 4) & 255, hh2 = (ent >> 12) & 7;
            const int fs = ((ent >> 15) & 1) ? 1 : -1;
            const float* xr = x + (rowbase + r) * 256;
            const float* wrow = WhT + (((long)hh2 << 8) + e) * 256;
            float acc = 0.0f;
            for (int k = 0; k < 256; k += 4) {   // sequential ascending chain, vector loads
                float4 xv = *reinterpret_cast<const float4*>(xr + k);
                float4 wv = *reinterpret_cast<const float4*>(wrow + k);
                acc = fmaf(xv.x, wv.x, acc);
                acc = fmaf(xv.y, wv.y, acc);
                acc = fmaf(xv.z, wv.z, acc);
                acc = fmaf(xv.w, wv.w, acc);
            }
            const float pre = __fadd_rn(acc, bh[hh2 * 256 + e]);
            const int es = (pre > 0.0f) ? 1 : -1;
            if (es != fs)
                atomicAdd(&((int*)(SM + LSH_OFF))[e * 16 + r], es - fs);
        }
    }
    __syncthreads();
    // ---- tail: stable counting sort + simv (bit-exact, r9-verified) ----
    if (tid < TN) {
        const int r = tid;
        const int* lshI = (const int*)(SM + LSH_OFF);
        const float* pe_over = (const float*)(SM + PE_OFF);
        const float* c_f = (const float*)(SM + CF_OFF);
        int* cw = (int*)(SM + CNT_OFF) + r * 16;
        for (int i = 0; i < 9; ++i) cw[i] = 0;
        for (int d = 0; d < 256; ++d) {
            int vv = lshI[d * 16 + r];
            cw[(vv + 8) >> 1] += 1;
        }
        int run = 0;
        for (int bin = 8; bin >= 0; --bin) { int c0 = cw[bin]; cw[bin] = run; run += c0; }
        float* valq = (float*)(SM + r * 1024);   // XSH/QTB region (dead)
        for (int d = 0; d < 256; ++d) {
            int vv = lshI[d * 16 + r];
            int bin = (vv + 8) >> 1;
            int j = cw[bin]++;
            valq[j] = __fadd_rn((float)vv, pe_over[d]);
        }
        float L0 = 0.f, L1 = 0.f, L2 = 0.f, L3 = 0.f,
              L4 = 0.f, L5 = 0.f, L6 = 0.f, L7 = 0.f;
        for (int i = 0; i < 256; i += 8) {
            L0 = fmaf(valq[i + 0], c_f[i + 0], L0);
            L1 = fmaf(valq[i + 1], c_f[i + 1], L1);
            L2 = fmaf(valq[i + 2], c_f[i + 2], L2);
            L3 = fmaf(valq[i + 3], c_f[i + 3], L3);
            L4 = fmaf(valq[i + 4], c_f[i + 4], L4);
            L5 = fmaf(valq[i + 5], c_f[i + 5], L5);
            L6 = fmaf(valq[i + 6], c_f[i + 6], L6);
            L7 = fmaf(valq[i + 7], c_f[i + 7], L7);
        }
        const float h0 = __fadd_rn(L0, L4);
        const float h1 = __fadd_rn(L1, L5);
        const float h2 = __fadd_rn(L2, L6);
        const float h3 = __fadd_rn(L3, L7);
        simv[rowbase + r] = __fadd_rn(__fadd_rn(h0, h2), __fadd_rn(h1, h3));
    }
}

// ---------------- K2: stable rank -> order ----------------
__global__ __launch_bounds__(256)
void k2_rank(const float* __restrict__ simv, int* __restrict__ order)
{
    __shared__ float s_l[4096];
    const int b = blockIdx.x >> 4;
    const int chunk = blockIdx.x & 15;
    const float* S = simv + (long)b * 4096;
    for (int i = threadIdx.x; i < 4096; i += 256) s_l[i] = S[i];
    __syncthreads();
    const int n = chunk * 256 + threadIdx.x;
    const float key = s_l[n];
    int cnt = 0;
    for (int m = 0; m < 4096; ++m) {
        float sm = s_l[m];
        cnt += (sm < key) ? 1 : ((sm == key && m < n) ? 1 : 0);
    }
    order[(long)b * 4096 + cnt] = n;
}

// ---------------- K3: value GEMM on gathered rows ----------------
__global__ __launch_bounds__(256, 2)
void k3_value(const float* __restrict__ z, const int* __restrict__ order,
              const float* __restrict__ Wv, const float* __restrict__ bv,
              float* __restrict__ v)
{
    __shared__ float zT[256 * XS3];
    __shared__ int sh_ord[TN3];
    const int tid = threadIdx.x;
    const long rowbase = (long)blockIdx.x * TN3;
    const long bbase = (rowbase >> 12) << 12;
    if (tid < TN3) sh_ord[tid] = order[rowbase + tid];
    __syncthreads();
    #pragma unroll
    for (int r = 0; r < TN3; ++r)
        zT[tid * XS3 + r] = z[(bbase + sh_ord[r]) * 256 + tid];
    float acc[TN3];
    #pragma unroll
    for (int r = 0; r < TN3; ++r) acc[r] = 0.0f;
    __syncthreads();
    const float* wc = Wv + tid;
    #pragma unroll 2
    for (int k = 0; k < 256; ++k) {
        float w = wc[k * 256];
        const float* zk = &zT[k * XS3];
        #pragma unroll
        for (int r4 = 0; r4 < TN3; r4 += 4) {
            float4 zv = *reinterpret_cast<const float4*>(zk + r4);
            acc[r4 + 0] = fmaf(zv.x, w, acc[r4 + 0]);
            acc[r4 + 1] = fmaf(zv.y, w, acc[r4 + 1]);
            acc[r4 + 2] = fmaf(zv.z, w, acc[r4 + 2]);
            acc[r4 + 3] = fmaf(zv.w, w, acc[r4 + 3]);
        }
    }
    const float bias = bv[tid];
    #pragma unroll
    for (int r = 0; r < TN3; ++r)
        v[(rowbase + r) * 256 + tid] = fmaxf(acc[r] + bias, 0.0f);
}

// ---------------- K4: windowed attention + residual + LayerNorm ----------------
__global__ __launch_bounds__(256)
void k4_attn_ln(const float* __restrict__ z, const float* __restrict__ v,
                const int* __restrict__ order, const float* __restrict__ x,
                const float* __restrict__ gamma, const float* __restrict__ beta,
                float* __restrict__ out)
{
    const int tid = threadIdx.x;
    const int wv = tid >> 6, lane = tid & 63;
    const long row = (long)blockIdx.x * 4 + wv;
    const int n = (int)(row & 4095);
    const long bbase = row - n;
    int start = n - 4;
    start = start < 0 ? 0 : start;
    start = start > (Nc - 9) ? (Nc - 9) : start;
    const int d0 = lane * 4;

    const int srcq = order[bbase + n];
    float4 q4 = *reinterpret_cast<const float4*>(&z[(bbase + srcq) * 256 + d0]);

    float t[9];
    #pragma unroll
    for (int w = 0; w < 9; ++w) {
        int srcm = order[bbase + start + w];
        float4 kv = *reinterpret_cast<const float4*>(&z[(bbase + srcm) * 256 + d0]);
        float p = q4.x * kv.x + q4.y * kv.y + q4.z * kv.z + q4.w * kv.w;
        #pragma unroll
        for (int off = 32; off > 0; off >>= 1) p += __shfl_xor(p, off);
        t[w] = p * 0.0625f;
    }
    float mx = t[0];
    #pragma unroll
    for (int w = 1; w < 9; ++w) mx = fmaxf(mx, t[w]);
    float pw[9], psum = 0.0f;
    #pragma unroll
    for (int w = 0; w < 9; ++w) { pw[w] = expf(t[w] - mx); psum += pw[w]; }
    const float pinv = 1.0f / psum;

    float4 a = make_float4(0.f, 0.f, 0.f, 0.f);
    #pragma unroll
    for (int w = 0; w < 9; ++w) {
        float4 vv = *reinterpret_cast<const float4*>(&v[(bbase + start + w) * 256 + d0]);
        float s = pw[w] * pinv;
        a.x = fmaf(vv.x, s, a.x);
        a.y = fmaf(vv.y, s, a.y);
        a.z = fmaf(vv.z, s, a.z);
        a.w = fmaf(vv.w, s, a.w);
    }
    float4 xv = *reinterpret_cast<const float4*>(&x[(bbase + n) * 256 + d0]);
    float4 y = make_float4(a.x + xv.x, a.y + xv.y, a.z + xv.z, a.w + xv.w);

    float s1 = y.x + y.y + y.z + y.w;
    float s2 = y.x * y.x + y.y * y.y + y.z * y.z + y.w * y.w;
    #pragma unroll
    for (int off = 32; off > 0; off >>= 1) {
        s1 += __shfl_xor(s1, off);
        s2 += __shfl_xor(s2, off);
    }
    const float mu = s1 * (1.0f / 256.0f);
    const float var = s2 * (1.0f / 256.0f) - mu * mu;
    const float istd = 1.0f / sqrtf(var + 0.001f);

    float4 g4 = *reinterpret_cast<const float4*>(&gamma[d0]);
    float4 b4 = *reinterpret_cast<const float4*>(&beta[d0]);
    float4 o;
    o.x = (y.x - mu) * istd * g4.x + b4.x;
    o.y = (y.y - mu) * istd * g4.y + b4.y;
    o.z = (y.z - mu) * istd * g4.z + b4.z;
    o.w = (y.w - mu) * istd * g4.w + b4.w;
    *reinterpret_cast<float4*>(&out[row * 256 + d0]) = o;
}

extern "C" void kernel_launch(void* const* d_in, const int* in_sizes, int n_in,
                              void* d_out, int out_size, void* d_ws, size_t ws_size,
                              hipStream_t stream)
{
    const float* x  = (const float*)d_in[0];
    const float* Wh = (const float*)d_in[1];
    const float* bh = (const float*)d_in[2];
    const float* Wd = (const float*)d_in[3];
    const float* bd = (const float*)d_in[4];
    const float* Wv = (const float*)d_in[5];
    const float* bv = (const float*)d_in[6];
    const float* g  = (const float*)d_in[7];
    const float* be = (const float*)d_in[8];
    float* out = (float*)d_out;

    char* ws = (char*)d_ws;
    float*          z     = (float*)ws;                       // 33554432 B
    float*          v     = (float*)(ws + 33554432);          // 33554432 B
    float*          simv  = (float*)(ws + 67108864);          // 131072 B
    int*            order = (int*)(ws + 67239936);            // 131072 B
    unsigned short* WdT   = (unsigned short*)(ws + 67371008); // 1048576 B
    unsigned short* WhH   = (unsigned short*)(ws + 68419584); // 1048576 B
    float*          WhT   = (float*)(ws + 69468160);          // 2097152 B

    const int rows = Bc * Nc;                                 // 32768
    k0_wdt<<<dim3(128), dim3(256), 0, stream>>>(Wd, WdT);
    k0_wht<<<dim3(128), dim3(256), 0, stream>>>(Wh, WhH, WhT);
    k1_head_down<<<dim3(rows / TN), dim3(256), 0, stream>>>(x, bh, WhT, WhH, WdT, bd, z, simv);
    k2_rank<<<dim3(Bc * 16), dim3(256), 0, stream>>>(simv, order);
    k3_value<<<dim3(rows / TN3), dim3(256), 0, stream>>>(z, order, Wv, bv, v);
    k4_attn_ln<<<dim3(rows / 4), dim3(256), 0, stream>>>(z, v, order, x, g, be, out);
}

// Round 14
// 744.170 us; speedup vs baseline: 1.5413x; 1.2321x over previous
//
#include <hip/hip_runtime.h>

constexpr int Bc = 8, Nc = 4096;

using short8 = __attribute__((ext_vector_type(8))) short;
using f32x4  = __attribute__((ext_vector_type(4))) float;

static __device__ __forceinline__ unsigned short f2bf(float f) {
    unsigned u = __float_as_uint(f);
    u += 0x7fffu + ((u >> 16) & 1u);     // RNE
    return (unsigned short)(u >> 16);
}
// XOR-swizzled byte offset for a [32][256] ushort LDS plane (16B-access safe)
static __device__ __forceinline__ int swz(int r, int k) {
    return (r << 9) + ((k << 1) ^ ((r & 7) << 4));
}

// ---------------- K0a: Wd [h][d][e] f32 -> WdT [h][e][d] bf16 ----------------
__global__ __launch_bounds__(256)
void k0_wdt(const float* __restrict__ Wd, unsigned short* __restrict__ WdT)
{
    __shared__ float tile[64][65];
    const int h  = blockIdx.x >> 4;
    const int t  = blockIdx.x & 15;
    const int kb = (t >> 2) * 64, eb = (t & 3) * 64;
    const int tid = threadIdx.x;
    {
        const int krow = tid >> 2, ec = (tid & 3) * 16;
        const float* src = Wd + h * 65536 + (kb + krow) * 256 + eb + ec;
        #pragma unroll
        for (int i = 0; i < 4; ++i) {
            float4 v = *reinterpret_cast<const float4*>(src + i * 4);
            tile[krow][ec + i * 4 + 0] = v.x;
            tile[krow][ec + i * 4 + 1] = v.y;
            tile[krow][ec + i * 4 + 2] = v.z;
            tile[krow][ec + i * 4 + 3] = v.w;
        }
    }
    __syncthreads();
    {
        const int erow = tid >> 2, dc = (tid & 3) * 16;
        unsigned short o[16];
        #pragma unroll
        for (int i = 0; i < 16; ++i) o[i] = f2bf(tile[dc + i][erow]);
        unsigned short* dst = WdT + h * 65536 + (eb + erow) * 256 + kb + dc;
        *reinterpret_cast<short8*>(dst)     = *reinterpret_cast<short8*>(&o[0]);
        *reinterpret_cast<short8*>(dst + 8) = *reinterpret_cast<short8*>(&o[8]);
    }
}

// ---------------- K0b: Wh [k][h][e] f32 -> WhH bf16 [h][e][k] + WhT f32 [h][e][k] ----------------
__global__ __launch_bounds__(256)
void k0_wht(const float* __restrict__ Wh, unsigned short* __restrict__ WhH,
            float* __restrict__ WhT)
{
    __shared__ float tile[64][65];
    const int h  = blockIdx.x >> 4;
    const int t  = blockIdx.x & 15;
    const int kb = (t >> 2) * 64, eb = (t & 3) * 64;
    const int tid = threadIdx.x;
    {
        const int krow = tid >> 2, ec = (tid & 3) * 16;
        const float* src = Wh + (kb + krow) * 2048 + h * 256 + eb + ec;
        #pragma unroll
        for (int i = 0; i < 4; ++i) {
            float4 v = *reinterpret_cast<const float4*>(src + i * 4);
            tile[krow][ec + i * 4 + 0] = v.x;
            tile[krow][ec + i * 4 + 1] = v.y;
            tile[krow][ec + i * 4 + 2] = v.z;
            tile[krow][ec + i * 4 + 3] = v.w;
        }
    }
    __syncthreads();
    {
        const int erow = tid >> 2, dc = (tid & 3) * 16;
        unsigned short o[16];
        float of[16];
        #pragma unroll
        for (int i = 0; i < 16; ++i) {
            of[i] = tile[dc + i][erow];
            o[i] = f2bf(of[i]);
        }
        const long base = (long)h * 65536 + (eb + erow) * 256 + kb + dc;
        *reinterpret_cast<short8*>(WhH + base)     = *reinterpret_cast<short8*>(&o[0]);
        *reinterpret_cast<short8*>(WhH + base + 8) = *reinterpret_cast<short8*>(&o[8]);
        #pragma unroll
        for (int i = 0; i < 16; i += 4)
            *reinterpret_cast<float4*>(WhT + base + i) = *reinterpret_cast<const float4*>(&of[i]);
    }
}

// ---------------- K0c: Wv [k][e] f32 -> WvT [e][k] bf16 ----------------
__global__ __launch_bounds__(256)
void k0_wvt(const float* __restrict__ Wv, unsigned short* __restrict__ WvT)
{
    __shared__ float tile[64][65];
    const int t  = blockIdx.x;
    const int kb = (t >> 2) * 64, eb = (t & 3) * 64;
    const int tid = threadIdx.x;
    {
        const int krow = tid >> 2, ec = (tid & 3) * 16;
        const float* src = Wv + (kb + krow) * 256 + eb + ec;
        #pragma unroll
        for (int i = 0; i < 4; ++i) {
            float4 v = *reinterpret_cast<const float4*>(src + i * 4);
            tile[krow][ec + i * 4 + 0] = v.x;
            tile[krow][ec + i * 4 + 1] = v.y;
            tile[krow][ec + i * 4 + 2] = v.z;
            tile[krow][ec + i * 4 + 3] = v.w;
        }
    }
    __syncthreads();
    {
        const int erow = tid >> 2, dc = (tid & 3) * 16;
        unsigned short o[16];
        #pragma unroll
        for (int i = 0; i < 16; ++i) o[i] = f2bf(tile[dc + i][erow]);
        unsigned short* dst = WvT + (eb + erow) * 256 + kb + dc;
        *reinterpret_cast<short8*>(dst)     = *reinterpret_cast<short8*>(&o[0]);
        *reinterpret_cast<short8*>(dst + 8) = *reinterpret_cast<short8*>(&o[8]);
    }
}

// LDS layout (bytes) for K1
#define XSH_OFF  0        // [32][256] ushort swz (x bf16) — dead after h loop
#define QTB_OFF  16384    // [32][256] ushort swz (q bf16) — dead after h loop
// LSHI overlays [0, 34816): int lshI[e*34 + r]
#define VALQ_OFF 35072    // 32 rows * 1024 B
#define PE_OFF   67840    // float[256]
#define CF_OFF   68864    // float[256]
#define CNT_OFF  69888    // int[32][16]
#define FCN_OFF  71936    // int
#define FLS_OFF  71952    // int[1536]
#define FLS_CAP  1536
#define GUARD    0.012f

// ---------------- K1: bf16-MFMA head GEMM (sign-guarded) + MFMA down GEMM ----------------
__global__ __launch_bounds__(256, 2)
void k1_head_down(const float* __restrict__ x,
                  const float* __restrict__ bh,
                  const float* __restrict__ WhT,
                  const unsigned short* __restrict__ WhH,
                  const unsigned short* __restrict__ WdT, const float* __restrict__ bd,
                  float* __restrict__ z, float* __restrict__ simv)
{
    __shared__ __align__(16) char SM[78336];

    const int tid = threadIdx.x;
    const long rowbase = (long)blockIdx.x * 32;
    const int wavei = tid >> 6, lane = tid & 63;
    const int mrow = lane & 15, kgrp = lane >> 4;
    const int ebase = wavei * 64 + mrow;
    const int kfo = kgrp * 8;

    short8 hB[4][4], dB[4][4];
    #pragma unroll
    for (int i = 0; i < 4; ++i)
        #pragma unroll
        for (int nf = 0; nf < 4; ++nf)
            hB[i][nf] = *reinterpret_cast<const short8*>(
                &WhH[(ebase + nf * 16) * 256 + i * 32 + kfo]);

    {   // XLA:CPU twin tables (CR libm via f64-round) — overlaps with hB flight
        const int d = tid;
        const float u = -((float)d * 0.00390625f);
        const float freq = (float)pow(10.0, (double)u);
        const float pe = (d & 1) ? (float)sin((double)freq)
                                 : (float)cos((double)freq);
        ((float*)(SM + PE_OFF))[d] = __fdiv_rn(pe, 0.4f);
        ((float*)(SM + CF_OFF))[d] = __fmul_rn(0.4f, (float)pow((double)0.6f, (double)d));
    }
    if (tid == 0) *((int*)(SM + FCN_OFF)) = 0;
    {   // x -> bf16 LDS (swizzled): thread handles row r, 32 k
        const int r = tid >> 3, kc = (tid & 7) * 32;
        const float* src = x + (rowbase + r) * 256 + kc;
        unsigned short oh[32];
        #pragma unroll
        for (int i = 0; i < 32; i += 4) {
            float4 v = *reinterpret_cast<const float4*>(src + i);
            oh[i + 0] = f2bf(v.x); oh[i + 1] = f2bf(v.y);
            oh[i + 2] = f2bf(v.z); oh[i + 3] = f2bf(v.w);
        }
        #pragma unroll
        for (int i = 0; i < 32; i += 8)
            *reinterpret_cast<short8*>(SM + XSH_OFF + swz(r, kc + i)) =
                *reinterpret_cast<short8*>(&oh[i]);
    }

    unsigned lshp[4] = {0u, 0u, 0u, 0u};    // 32 nibble counters (statically indexed)
    f32x4 dacc[2][4];
    #pragma unroll
    for (int mt = 0; mt < 2; ++mt)
        #pragma unroll
        for (int nf = 0; nf < 4; ++nf) dacc[mt][nf] = (f32x4){0.f, 0.f, 0.f, 0.f};

    __syncthreads();

    for (int h = 0; h < 8; ++h) {
        const unsigned short* whh = WhH + ((long)h << 16);
        const unsigned short* wdh = WdT + ((long)h << 16);
        float bias[4];
        #pragma unroll
        for (int nf = 0; nf < 4; ++nf) bias[nf] = bh[(h << 8) + ebase + nf * 16];

        // ---- head GEMM: ring-4 prefetch; down-B slices 0..3 issued here ----
        f32x4 hacc[2][4];
        #pragma unroll
        for (int mt = 0; mt < 2; ++mt)
            #pragma unroll
            for (int nf = 0; nf < 4; ++nf) hacc[mt][nf] = (f32x4){0.f, 0.f, 0.f, 0.f};
        #pragma unroll
        for (int kt = 0; kt < 8; ++kt) {
            const int k0 = kt * 32 + kfo;
            short8 a0 = *reinterpret_cast<const short8*>(SM + XSH_OFF + swz(mrow, k0));
            short8 a1 = *reinterpret_cast<const short8*>(SM + XSH_OFF + swz(16 + mrow, k0));
            if (kt < 4) {
                #pragma unroll
                for (int nf = 0; nf < 4; ++nf)
                    dB[kt][nf] = *reinterpret_cast<const short8*>(
                        &wdh[(ebase + nf * 16) * 256 + kt * 32 + kfo]);
            }
            #pragma unroll
            for (int nf = 0; nf < 4; ++nf) {
                hacc[0][nf] = __builtin_amdgcn_mfma_f32_16x16x32_bf16(a0, hB[kt & 3][nf], hacc[0][nf], 0, 0, 0);
                hacc[1][nf] = __builtin_amdgcn_mfma_f32_16x16x32_bf16(a1, hB[kt & 3][nf], hacc[1][nf], 0, 0, 0);
            }
            if (kt < 4) {
                #pragma unroll
                for (int nf = 0; nf < 4; ++nf)
                    hB[kt][nf] = *reinterpret_cast<const short8*>(
                        &whh[(ebase + nf * 16) * 256 + (kt + 4) * 32 + kfo]);
            }
        }
        // ---- signs / guard-list / qTb ----
        #pragma unroll
        for (int mt = 0; mt < 2; ++mt) {
            #pragma unroll
            for (int nf = 0; nf < 4; ++nf) {
                const int e = ebase + nf * 16;
                #pragma unroll
                for (int reg = 0; reg < 4; ++reg) {
                    const int r = mt * 16 + kgrp * 4 + reg;
                    const float pre = __fadd_rn(hacc[mt][nf][reg], bias[nf]);
                    const unsigned pos = (pre > 0.0f) ? 1u : 0u;
                    const int j = mt * 16 + nf * 4 + reg;
                    lshp[j >> 3] += pos << (4 * (j & 7));
                    if (fabsf(pre) < GUARD) {
                        int idx = atomicAdd((int*)(SM + FCN_OFF), 1);
                        if (idx < FLS_CAP)
                            ((int*)(SM + FLS_OFF))[idx] =
                                r | (e << 5) | (h << 13) | ((int)pos << 16);
                    }
                    *reinterpret_cast<unsigned short*>(SM + QTB_OFF + swz(r, e)) =
                        f2bf(fmaxf(pre, 0.0f));
                }
            }
        }
        __syncthreads();   // qTb ready
        // ---- down GEMM: ring-4; slices 4..7 + next-h head slices issued here ----
        #pragma unroll
        for (int ks = 0; ks < 8; ++ks) {
            const int k0 = ks * 32 + kfo;
            short8 a0 = *reinterpret_cast<const short8*>(SM + QTB_OFF + swz(mrow, k0));
            short8 a1 = *reinterpret_cast<const short8*>(SM + QTB_OFF + swz(16 + mrow, k0));
            #pragma unroll
            for (int nf = 0; nf < 4; ++nf) {
                dacc[0][nf] = __builtin_amdgcn_mfma_f32_16x16x32_bf16(a0, dB[ks & 3][nf], dacc[0][nf], 0, 0, 0);
                dacc[1][nf] = __builtin_amdgcn_mfma_f32_16x16x32_bf16(a1, dB[ks & 3][nf], dacc[1][nf], 0, 0, 0);
            }
            if (ks < 4) {
                #pragma unroll
                for (int nf = 0; nf < 4; ++nf)
                    dB[ks][nf] = *reinterpret_cast<const short8*>(
                        &wdh[(ebase + nf * 16) * 256 + (ks + 4) * 32 + kfo]);
            } else if (h < 7) {
                #pragma unroll
                for (int nf = 0; nf < 4; ++nf)
                    hB[ks - 4][nf] = *reinterpret_cast<const short8*>(
                        &WhH[((long)(h + 1) << 16) + (ebase + nf * 16) * 256 + (ks - 4) * 32 + kfo]);
            }
        }
        __syncthreads();   // qTb free for next h
    }
    // ---- epilogue: z = relu(dacc + bd) ----
    #pragma unroll
    for (int mt = 0; mt < 2; ++mt) {
        #pragma unroll
        for (int nf = 0; nf < 4; ++nf) {
            const int e = ebase + nf * 16;
            const float b = bd[e];
            #pragma unroll
            for (int reg = 0; reg < 4; ++reg)
                z[(rowbase + mt * 16 + kgrp * 4 + reg) * 256 + e] =
                    fmaxf(dacc[mt][nf][reg] + b, 0.0f);
        }
    }
    // ---- lsh decode + write (lshI overlays dead xsh/qtb) ----
    {
        int* lshI = (int*)SM;
        #pragma unroll
        for (int mt = 0; mt < 2; ++mt)
            #pragma unroll
            for (int nf = 0; nf < 4; ++nf) {
                const int e = ebase + nf * 16;
                #pragma unroll
                for (int reg = 0; reg < 4; ++reg) {
                    const int r = mt * 16 + kgrp * 4 + reg;
                    const int j = mt * 16 + nf * 4 + reg;
                    const unsigned p = (lshp[j >> 3] >> (4 * (j & 7))) & 15u;
                    lshI[e * 34 + r] = 2 * (int)p - 8;
                }
            }
    }
    __syncthreads();
    // ---- guard: exact ascending-k f32 chain (contiguous WhT rows) ----
    {
        int* lshI = (int*)SM;
        int n = *((int*)(SM + FCN_OFF));
        n = n < FLS_CAP ? n : FLS_CAP;
        for (int i = tid; i < n; i += 256) {
            const int ent = ((int*)(SM + FLS_OFF))[i];
            const int r = ent & 31, e = (ent >> 5) & 255, hh2 = (ent >> 13) & 7;
            const int fs = ((ent >> 16) & 1) ? 1 : -1;
            const float* xr = x + (rowbase + r) * 256;
            const float* wrow = WhT + (((long)hh2 << 8) + e) * 256;
            float acc = 0.0f;
            for (int k = 0; k < 256; k += 4) {
                float4 xv = *reinterpret_cast<const float4*>(xr + k);
                float4 wv = *reinterpret_cast<const float4*>(wrow + k);
                acc = fmaf(xv.x, wv.x, acc);
                acc = fmaf(xv.y, wv.y, acc);
                acc = fmaf(xv.z, wv.z, acc);
                acc = fmaf(xv.w, wv.w, acc);
            }
            const float pre = __fadd_rn(acc, bh[hh2 * 256 + e]);
            const int es = (pre > 0.0f) ? 1 : -1;
            if (es != fs)
                atomicAdd(&lshI[e * 34 + r], es - fs);
        }
    }
    __syncthreads();
    // ---- tail: stable counting sort + simv (bit-exact, r9-verified) ----
    if (tid < 32) {
        const int r = tid;
        const int* lshI = (const int*)SM;
        const float* pe_over = (const float*)(SM + PE_OFF);
        const float* c_f = (const float*)(SM + CF_OFF);
        int* cw = (int*)(SM + CNT_OFF) + r * 16;
        for (int i = 0; i < 9; ++i) cw[i] = 0;
        for (int d = 0; d < 256; ++d) {
            int vv = lshI[d * 34 + r];
            cw[(vv + 8) >> 1] += 1;
        }
        int run = 0;
        for (int bin = 8; bin >= 0; --bin) { int c0 = cw[bin]; cw[bin] = run; run += c0; }
        float* valq = (float*)(SM + VALQ_OFF + r * 1024);
        for (int d = 0; d < 256; ++d) {
            int vv = lshI[d * 34 + r];
            int bin = (vv + 8) >> 1;
            int j = cw[bin]++;
            valq[j] = __fadd_rn((float)vv, pe_over[d]);
        }
        float L0 = 0.f, L1 = 0.f, L2 = 0.f, L3 = 0.f,
              L4 = 0.f, L5 = 0.f, L6 = 0.f, L7 = 0.f;
        for (int i = 0; i < 256; i += 8) {
            L0 = fmaf(valq[i + 0], c_f[i + 0], L0);
            L1 = fmaf(valq[i + 1], c_f[i + 1], L1);
            L2 = fmaf(valq[i + 2], c_f[i + 2], L2);
            L3 = fmaf(valq[i + 3], c_f[i + 3], L3);
            L4 = fmaf(valq[i + 4], c_f[i + 4], L4);
            L5 = fmaf(valq[i + 5], c_f[i + 5], L5);
            L6 = fmaf(valq[i + 6], c_f[i + 6], L6);
            L7 = fmaf(valq[i + 7], c_f[i + 7], L7);
        }
        const float h0 = __fadd_rn(L0, L4);
        const float h1 = __fadd_rn(L1, L5);
        const float h2 = __fadd_rn(L2, L6);
        const float h3 = __fadd_rn(L3, L7);
        simv[rowbase + r] = __fadd_rn(__fadd_rn(h0, h2), __fadd_rn(h1, h3));
    }
}

// ---------------- K2: stable rank -> order ----------------
__global__ __launch_bounds__(256)
void k2_rank(const float* __restrict__ simv, int* __restrict__ order)
{
    __shared__ float s_l[4096];
    const int b = blockIdx.x >> 4;
    const int chunk = blockIdx.x & 15;
    const float* S = simv + (long)b * 4096;
    for (int i = threadIdx.x; i < 4096; i += 256) s_l[i] = S[i];
    __syncthreads();
    const int n = chunk * 256 + threadIdx.x;
    const float key = s_l[n];
    int cnt = 0;
    for (int m = 0; m < 4096; ++m) {
        float sm = s_l[m];
        cnt += (sm < key) ? 1 : ((sm == key && m < n) ? 1 : 0);
    }
    order[(long)b * 4096 + cnt] = n;
}

// ---------------- K3: value GEMM on gathered rows (bf16 MFMA) ----------------
__global__ __launch_bounds__(256, 3)
void k3_value(const float* __restrict__ z, const int* __restrict__ order,
              const unsigned short* __restrict__ WvT, const float* __restrict__ bv,
              float* __restrict__ v)
{
    __shared__ __align__(16) unsigned short ZB[32 * 256];   // swizzled bf16
    __shared__ int ord[32];
    const int tid = threadIdx.x;
    const long rowbase = (long)blockIdx.x * 32;
    const long bbase = (rowbase >> 12) << 12;
    const int wavei = tid >> 6, lane = tid & 63;
    const int mrow = lane & 15, kgrp = lane >> 4;
    const int ebase = wavei * 64 + mrow;
    const int kfo = kgrp * 8;

    if (tid < 32) ord[tid] = order[rowbase + tid];

    short8 vB[4][4];
    #pragma unroll
    for (int i = 0; i < 4; ++i)
        #pragma unroll
        for (int nf = 0; nf < 4; ++nf)
            vB[i][nf] = *reinterpret_cast<const short8*>(
                &WvT[(ebase + nf * 16) * 256 + i * 32 + kfo]);

    __syncthreads();   // ord visible
    {   // gather z rows (sorted order) -> bf16 LDS
        const int r = tid >> 3, kc = (tid & 7) * 32;
        const float* src = z + (bbase + ord[r]) * 256 + kc;
        unsigned short oh[32];
        #pragma unroll
        for (int i = 0; i < 32; i += 4) {
            float4 vv = *reinterpret_cast<const float4*>(src + i);
            oh[i + 0] = f2bf(vv.x); oh[i + 1] = f2bf(vv.y);
            oh[i + 2] = f2bf(vv.z); oh[i + 3] = f2bf(vv.w);
        }
        #pragma unroll
        for (int i = 0; i < 32; i += 8)
            *reinterpret_cast<short8*>((char*)ZB + swz(r, kc + i)) =
                *reinterpret_cast<short8*>(&oh[i]);
    }
    __syncthreads();

    f32x4 acc[2][4];
    #pragma unroll
    for (int mt = 0; mt < 2; ++mt)
        #pragma unroll
        for (int nf = 0; nf < 4; ++nf) acc[mt][nf] = (f32x4){0.f, 0.f, 0.f, 0.f};
    #pragma unroll
    for (int kt = 0; kt < 8; ++kt) {
        const int k0 = kt * 32 + kfo;
        short8 a0 = *reinterpret_cast<const short8*>((char*)ZB + swz(mrow, k0));
        short8 a1 = *reinterpret_cast<const short8*>((char*)ZB + swz(16 + mrow, k0));
        #pragma unroll
        for (int nf = 0; nf < 4; ++nf) {
            acc[0][nf] = __builtin_amdgcn_mfma_f32_16x16x32_bf16(a0, vB[kt & 3][nf], acc[0][nf], 0, 0, 0);
            acc[1][nf] = __builtin_amdgcn_mfma_f32_16x16x32_bf16(a1, vB[kt & 3][nf], acc[1][nf], 0, 0, 0);
        }
        if (kt < 4) {
            #pragma unroll
            for (int nf = 0; nf < 4; ++nf)
                vB[kt][nf] = *reinterpret_cast<const short8*>(
                    &WvT[(ebase + nf * 16) * 256 + (kt + 4) * 32 + kfo]);
        }
    }
    #pragma unroll
    for (int mt = 0; mt < 2; ++mt) {
        #pragma unroll
        for (int nf = 0; nf < 4; ++nf) {
            const int e = ebase + nf * 16;
            const float b = bv[e];
            #pragma unroll
            for (int reg = 0; reg < 4; ++reg)
                v[(rowbase + mt * 16 + kgrp * 4 + reg) * 256 + e] =
                    fmaxf(acc[mt][nf][reg] + b, 0.0f);
        }
    }
}

// ---------------- K4: windowed attention + residual + LayerNorm ----------------
__global__ __launch_bounds__(256)
void k4_attn_ln(const float* __restrict__ z, const float* __restrict__ v,
                const int* __restrict__ order, const float* __restrict__ x,
                const float* __restrict__ gamma, const float* __restrict__ beta,
                float* __restrict__ out)
{
    const int tid = threadIdx.x;
    const int wv = tid >> 6, lane = tid & 63;
    const long row = (long)blockIdx.x * 4 + wv;
    const int n = (int)(row & 4095);
    const long bbase = row - n;
    int start = n - 4;
    start = start < 0 ? 0 : start;
    start = start > (Nc - 9) ? (Nc - 9) : start;
    const int d0 = lane * 4;

    const int srcq = order[bbase + n];
    float4 q4 = *reinterpret_cast<const float4*>(&z[(bbase + srcq) * 256 + d0]);

    float t[9];
    #pragma unroll
    for (int w = 0; w < 9; ++w) {
        int srcm = order[bbase + start + w];
        float4 kv = *reinterpret_cast<const float4*>(&z[(bbase + srcm) * 256 + d0]);
        float p = q4.x * kv.x + q4.y * kv.y + q4.z * kv.z + q4.w * kv.w;
        #pragma unroll
        for (int off = 32; off > 0; off >>= 1) p += __shfl_xor(p, off);
        t[w] = p * 0.0625f;
    }
    float mx = t[0];
    #pragma unroll
    for (int w = 1; w < 9; ++w) mx = fmaxf(mx, t[w]);
    float pw[9], psum = 0.0f;
    #pragma unroll
    for (int w = 0; w < 9; ++w) { pw[w] = expf(t[w] - mx); psum += pw[w]; }
    const float pinv = 1.0f / psum;

    float4 a = make_float4(0.f, 0.f, 0.f, 0.f);
    #pragma unroll
    for (int w = 0; w < 9; ++w) {
        float4 vv = *reinterpret_cast<const float4*>(&v[(bbase + start + w) * 256 + d0]);
        float s = pw[w] * pinv;
        a.x = fmaf(vv.x, s, a.x);
        a.y = fmaf(vv.y, s, a.y);
        a.z = fmaf(vv.z, s, a.z);
        a.w = fmaf(vv.w, s, a.w);
    }
    float4 xv = *reinterpret_cast<const float4*>(&x[(bbase + n) * 256 + d0]);
    float4 y = make_float4(a.x + xv.x, a.y + xv.y, a.z + xv.z, a.w + xv.w);

    float s1 = y.x + y.y + y.z + y.w;
    float s2 = y.x * y.x + y.y * y.y + y.z * y.z + y.w * y.w;
    #pragma unroll
    for (int off = 32; off > 0; off >>= 1) {
        s1 += __shfl_xor(s1, off);
        s2 += __shfl_xor(s2, off);
    }
    const float mu = s1 * (1.0f / 256.0f);
    const float var = s2 * (1.0f / 256.0f) - mu * mu;
    const float istd = 1.0f / sqrtf(var + 0.001f);

    float4 g4 = *reinterpret_cast<const float4*>(&gamma[d0]);
    float4 b4 = *reinterpret_cast<const float4*>(&beta[d0]);
    float4 o;
    o.x = (y.x - mu) * istd * g4.x + b4.x;
    o.y = (y.y - mu) * istd * g4.y + b4.y;
    o.z = (y.z - mu) * istd * g4.z + b4.z;
    o.w = (y.w - mu) * istd * g4.w + b4.w;
    *reinterpret_cast<float4*>(&out[row * 256 + d0]) = o;
}

extern "C" void kernel_launch(void* const* d_in, const int* in_sizes, int n_in,
                              void* d_out, int out_size, void* d_ws, size_t ws_size,
                              hipStream_t stream)
{
    const float* x  = (const float*)d_in[0];
    const float* Wh = (const float*)d_in[1];
    const float* bh = (const float*)d_in[2];
    const float* Wd = (const float*)d_in[3];
    const float* bd = (const float*)d_in[4];
    const float* Wv = (const float*)d_in[5];
    const float* bv = (const float*)d_in[6];
    const float* g  = (const float*)d_in[7];
    const float* be = (const float*)d_in[8];
    float* out = (float*)d_out;

    char* ws = (char*)d_ws;
    float*          z     = (float*)ws;                       // 33554432 B
    float*          v     = (float*)(ws + 33554432);          // 33554432 B
    float*          simv  = (float*)(ws + 67108864);          // 131072 B
    int*            order = (int*)(ws + 67239936);            // 131072 B
    unsigned short* WdT   = (unsigned short*)(ws + 67371008); // 1048576 B
    unsigned short* WhH   = (unsigned short*)(ws + 68419584); // 1048576 B
    float*          WhT   = (float*)(ws + 69468160);          // 2097152 B
    unsigned short* WvT   = (unsigned short*)(ws + 71565312); // 131072 B

    const int rows = Bc * Nc;                                 // 32768
    k0_wdt<<<dim3(128), dim3(256), 0, stream>>>(Wd, WdT);
    k0_wht<<<dim3(128), dim3(256), 0, stream>>>(Wh, WhH, WhT);
    k0_wvt<<<dim3(16), dim3(256), 0, stream>>>(Wv, WvT);
    k1_head_down<<<dim3(rows / 32), dim3(256), 0, stream>>>(x, bh, WhT, WhH, WdT, bd, z, simv);
    k2_rank<<<dim3(Bc * 16), dim3(256), 0, stream>>>(simv, order);
    k3_value<<<dim3(rows / 32), dim3(256), 0, stream>>>(z, order, WvT, bv, v);
    k4_attn_ln<<<dim3(rows / 4), dim3(256), 0, stream>>>(z, v, order, x, g, be, out);
}